// Round 2
// baseline (310.606 us; speedup 1.0000x reference)
//
#include <hip/hip_runtime.h>

#define NXc 468
#define NYc 468
#define CANVASc (468 * 468)   // 219024
#define NPTS 400000
#define RUN 16
#define NRUNS (NPTS / RUN)    // 25000 exactly

#define PCMIN_X (-74.88f)
#define PCMIN_Y (-74.88f)
#define VOX_X 0.32f
#define VOX_Y 0.32f
#define OFF_X (-74.72f)
#define OFF_Y (-74.72f)
#define OFF_Z (1.0f)

typedef __attribute__((ext_vector_type(8))) short v8s;   // 8 bf16 (4 VGPRs)
typedef __attribute__((ext_vector_type(4))) float v4f;   // MFMA acc

static_assert(sizeof(__bf16) == 2, "bf16 must be 2 bytes");

__device__ __forceinline__ int rli(int x, int p) {
    return __builtin_amdgcn_readlane(x, p);
}

// Native bf16 split: hi = RNE(f), lo = RNE(f - hi).
// gfx950 lowers float->__bf16 fptrunc to v_cvt_pk_bf16_f32 (paired) — far
// fewer VALU insts than the manual add/shift RNE sequence.
__device__ __forceinline__ void split8(const float* f, v8s& h, v8s& l) {
    #pragma unroll
    for (int i = 0; i < 8; i += 2) {
        __bf16 h0 = (__bf16)f[i];
        __bf16 h1 = (__bf16)f[i + 1];
        h[i]     = __builtin_bit_cast(short, h0);
        h[i + 1] = __builtin_bit_cast(short, h1);
        float l0 = f[i]     - (float)h0;
        float l1 = f[i + 1] - (float)h1;
        l[i]     = __builtin_bit_cast(short, (__bf16)l0);
        l[i + 1] = __builtin_bit_cast(short, (__bf16)l1);
    }
}

__device__ __forceinline__ int voxel_cell(float x, float y, int& cx, int& cy) {
    cx = (int)floorf((x - PCMIN_X) / VOX_X);
    cy = (int)floorf((y - PCMIN_Y) / VOX_Y);
    cx = min(max(cx, 0), NXc - 1);
    cy = min(max(cy, 0), NYc - 1);
    return cy * NXc + cx;
}

// Pass 0: per-voxel counts + per-point voxel key + per-voxel xyz sums.
// (vsum via float atomics replaces the old sorted-order kA0 dispatch;
//  ~1.8 pts/voxel -> negligible contention, reorder error ~1e-5.)
__global__ __launch_bounds__(256) void k_stats(const float* __restrict__ pts,
                                               int* __restrict__ cnt,
                                               int* __restrict__ key,
                                               float4* __restrict__ vsum4) {
    int i = blockIdx.x * 256 + threadIdx.x;
    if (i >= NPTS) return;
    const float* pp = pts + (size_t)i * 5;
    float x = pp[0], y = pp[1], z = pp[2];
    int cx, cy;
    int fl = voxel_cell(x, y, cx, cy);
    key[i] = fl;
    atomicAdd(&cnt[fl], 1);
    float* s = (float*)&vsum4[fl];
    unsafeAtomicAdd(s + 0, x);
    unsafeAtomicAdd(s + 1, y);
    unsafeAtomicAdd(s + 2, z);
}

// Pass 1: exclusive-scan alloc -> cursor
__global__ __launch_bounds__(256) void k_alloc(const int* __restrict__ cnt,
                                               int* __restrict__ cursor,
                                               int* __restrict__ gcur) {
    int v = blockIdx.x * 256 + threadIdx.x;
    int lane = threadIdx.x & 63;
    int c = (v < CANVASc) ? cnt[v] : 0;
    int scan = c;
    #pragma unroll
    for (int off = 1; off < 64; off <<= 1) {
        int t = __shfl_up(scan, off, 64);
        if (lane >= off) scan += t;
    }
    int total = __shfl(scan, 63, 64);
    int base = 0;
    if (lane == 0 && total > 0) base = atomicAdd(gcur, total);
    base = __shfl(base, 0, 64);
    if (v < CANVASc) cursor[v] = base + scan - c;
}

// Pass 2: index-only scatter (4B random writes instead of 20B records)
__global__ __launch_bounds__(256) void k_scatter(const int* __restrict__ key,
                                                 int* __restrict__ cursor,
                                                 int* __restrict__ ord) {
    int i = blockIdx.x * 256 + threadIdx.x;
    if (i >= NPTS) return;
    int fl = key[i];
    int pos = atomicAdd(&cursor[fl], 1);
    ord[pos] = i;
}

// gather one point record (random 20B, pts is L2/L3-warm)
__device__ __forceinline__ void gather_pt(const float* __restrict__ pts, int pi,
                                          float4& A, float& e1) {
    const float* pp = pts + (size_t)pi * 5;
    __builtin_memcpy(&A, pp, 16);   // 4B-aligned dwordx4
    e1 = pp[4];
}

// k_div: vsum -> vmean in place
__global__ __launch_bounds__(256) void k_div(const int* __restrict__ cnt,
                                             float4* __restrict__ vsum4) {
    int v = blockIdx.x * 256 + threadIdx.x;
    if (v >= CANVASc) return;
    int c = cnt[v];
    float inv = (c > 0) ? 1.0f / (float)c : 0.f;
    float4 s = vsum4[v];
    vsum4[v] = make_float4(s.x * inv, s.y * inv, s.z * inv, 0.f);
}

// kW: bf16 hi/lo B-fragments for W2 (4 tiles x 4 K-chunks) and W1 (4 tiles,
// K=32 single chunk, rows >= 11 zero). B[k][n]: n=lane&15, k=c*32+(lane>>4)*8+i.
__global__ __launch_bounds__(256) void kW(const float* __restrict__ W1,
                                          const float* __restrict__ W2,
                                          v8s* __restrict__ w1frag,
                                          v8s* __restrict__ w2frag) {
    int tid = blockIdx.x * 256 + threadIdx.x;   // 1280 total
    if (tid < 1024) {
        int f = tid >> 6, lane = tid & 63;
        int t = f >> 2, c = f & 3;
        int q = lane >> 4, n = lane & 15;
        float v[8];
        #pragma unroll
        for (int i = 0; i < 8; i++) v[i] = W2[(c * 32 + q * 8 + i) * 64 + t * 16 + n];
        v8s h, l;
        split8(v, h, l);
        w2frag[(f * 2 + 0) * 64 + lane] = h;
        w2frag[(f * 2 + 1) * 64 + lane] = l;
    } else if (tid < 1280) {
        int f = (tid - 1024) >> 6, lane = (tid - 1024) & 63;
        int q = lane >> 4, n = lane & 15;
        float v[8];
        #pragma unroll
        for (int i = 0; i < 8; i++) {
            int k = q * 8 + i;
            v[i] = (k < 11) ? W1[k * 64 + f * 16 + n] : 0.f;
        }
        v8s h, l;
        split8(v, h, l);
        w1frag[(f * 2 + 0) * 64 + lane] = h;
        w1frag[(f * 2 + 1) * 64 + lane] = l;
    }
}

// Per-lane prep: lanes 0..15 gather point base+j + vmean; lanes 16/17 peek
// neighbor voxels for run-edge detection.
struct PtRegs {
    float4 A;
    float  e1, fcx, fcy, fcz;
    float  mx, my, mz;
    int    vx;
};
__device__ __forceinline__ PtRegs load_pt(const int* __restrict__ ord,
                                          const float* __restrict__ pts,
                                          const float4* __restrict__ vmean4,
                                          int base, int j) {
    PtRegs r;
    r.A = make_float4(0.f, 0.f, 0.f, 0.f);
    r.e1 = r.fcx = r.fcy = r.fcz = r.mx = r.my = r.mz = 0.f;
    r.vx = -1;
    int idx = -1;
    if (j < RUN) idx = base + j;
    else if (j == 16) idx = (base + RUN < NPTS) ? base + RUN : -1;
    else if (j == 17) idx = base - 1;
    if (idx >= 0) {
        int pi = ord[idx];
        float4 A; float e1;
        gather_pt(pts, pi, A, e1);
        int cx, cy;
        int vv = voxel_cell(A.x, A.y, cx, cy);
        r.vx = vv;
        if (j < RUN) {
            r.A = A;
            r.e1 = e1;
            r.fcx = A.x - (cx * VOX_X + OFF_X);
            r.fcy = A.y - (cy * VOX_Y + OFF_Y);
            r.fcz = A.z - OFF_Z;
            float4 m = vmean4[vv];
            r.mx = m.x; r.my = m.y; r.mz = m.z;
        }
    }
    return r;
}

#define PSTR 68   // LDS row stride (floats)

// Shared phase-1: features -> LDS rows -> MFMA (K=32, 12 mfma) -> relu(D) -> LDS.
// On return s_pf rows 0..15 hold relu'd pf1[p][0..63].
__device__ __forceinline__ void phase1_mfma(float (*s_pf)[PSTR], const PtRegs& P,
                                            const v8s* __restrict__ w1frag, int j) {
    if (j < RUN) {
        float* row = s_pf[j];
        row[0] = P.A.x; row[1] = P.A.y; row[2] = P.A.z; row[3] = P.A.w; row[4] = P.e1;
        row[5] = P.A.x - P.mx; row[6] = P.A.y - P.my; row[7] = P.A.z - P.mz;
        row[8] = P.fcx; row[9] = P.fcy; row[10] = P.fcz;
        #pragma unroll
        for (int t = 11; t < 16; t++) row[t] = 0.f;
    }
    __builtin_amdgcn_wave_barrier();

    const int m = j & 15, q = j >> 4;
    v8s fh = {0,0,0,0,0,0,0,0}, fl_ = {0,0,0,0,0,0,0,0};
    if (q < 2) {
        float f8[8];
        #pragma unroll
        for (int i = 0; i < 8; i++) f8[i] = s_pf[m][q * 8 + i];
        split8(f8, fh, fl_);
    }
    v4f d[4];
    #pragma unroll
    for (int t = 0; t < 4; t++) {
        v8s bh = w1frag[(t * 2 + 0) * 64 + j];
        v8s bl = w1frag[(t * 2 + 1) * 64 + j];
        v4f acc = {0.f, 0.f, 0.f, 0.f};
        acc = __builtin_amdgcn_mfma_f32_16x16x32_bf16(fh,  bh, acc, 0, 0, 0);
        acc = __builtin_amdgcn_mfma_f32_16x16x32_bf16(fl_, bh, acc, 0, 0, 0);
        acc = __builtin_amdgcn_mfma_f32_16x16x32_bf16(fh,  bl, acc, 0, 0, 0);
        d[t] = acc;
    }
    __builtin_amdgcn_wave_barrier();   // feature reads complete before overwrite
    #pragma unroll
    for (int t = 0; t < 4; t++)
        #pragma unroll
        for (int r = 0; r < 4; r++)
            s_pf[q * 4 + r][t * 16 + m] = fmaxf(d[t][r], 0.f);
    __builtin_amdgcn_wave_barrier();
}

// kA: v1 = segment_max(pf1) with edge-detected atomics.
__global__ __launch_bounds__(256) void kA(const int* __restrict__ ord,
                                          const float* __restrict__ pts,
                                          const float4* __restrict__ vmean4,
                                          const v8s* __restrict__ w1frag,
                                          float* __restrict__ v1) {
    __shared__ float s_pf[4][RUN][PSTR];
    int wslot = threadIdx.x >> 6;
    int wave = blockIdx.x * 4 + wslot;
    int j = threadIdx.x & 63;
    int base = wave * RUN;

    PtRegs P = load_pt(ord, pts, vmean4, base, j);
    phase1_mfma(s_pf[wslot], P, w1frag, j);

    const int first = rli(P.vx, 0), last = rli(P.vx, RUN - 1);
    const bool firstExt = (rli(P.vx, 17) == first);
    const bool lastExt  = (rli(P.vx, 16) == last);
    int vprev = first;
    float smax = 0.f;
    for (int p = 0; p < RUN; p++) {
        int vp = rli(P.vx, p);
        if (vp != vprev) {
            size_t o = (size_t)vprev * 64 + j;
            bool ua = (vprev == first && firstExt) || (vprev == last && lastExt);
            if (ua) atomicMax((int*)v1 + o, __float_as_int(smax));
            else v1[o] = smax;
            vprev = vp; smax = 0.f;
        }
        smax = fmaxf(smax, s_pf[wslot][p][j]);
    }
    {
        size_t o = (size_t)vprev * 64 + j;
        bool ua = (vprev == first && firstExt) || (vprev == last && lastExt);
        if (ua) atomicMax((int*)v1 + o, __float_as_int(smax));
        else v1[o] = smax;
    }
}

// kB: D[p][j] = [pf1[p], v1[vox(p)]] @ W2 via MFMA -> segment max -> out.
__global__ __launch_bounds__(256) void kB(const int* __restrict__ ord,
                                          const float* __restrict__ pts,
                                          const float4* __restrict__ vmean4,
                                          const v8s* __restrict__ w1frag,
                                          const v8s* __restrict__ w2frag,
                                          const float* __restrict__ v1,
                                          float* __restrict__ out) {
    __shared__ float s_pf[4][RUN][PSTR];
    int wslot = threadIdx.x >> 6;
    int wave = blockIdx.x * 4 + wslot;
    int j = threadIdx.x & 63;
    int base = wave * RUN;

    PtRegs P = load_pt(ord, pts, vmean4, base, j);
    phase1_mfma(s_pf[wslot], P, w1frag, j);

    const int m = j & 15, q = j >> 4;

    // A-frags: chunks 0,1 = pf1 rows (lane-distinct LDS reads)
    v8s ah[4], al[4];
    #pragma unroll
    for (int c = 0; c < 2; c++) {
        float f[8];
        #pragma unroll
        for (int i = 0; i < 8; i++) f[i] = s_pf[wslot][m][c * 32 + q * 8 + i];
        split8(f, ah[c], al[c]);
    }
    // chunks 2,3 = v1[vox(point m)] (segment-constant: rides inside the acc)
    int vx_m = __builtin_amdgcn_ds_bpermute(m << 2, P.vx);
    {
        const float* vr = v1 + (size_t)vx_m * 64 + q * 8;
        #pragma unroll
        for (int c = 2; c < 4; c++) {
            float f[8];
            #pragma unroll
            for (int i = 0; i < 8; i++) f[i] = vr[(c - 2) * 32 + i];
            split8(f, ah[c], al[c]);
        }
    }
    __builtin_amdgcn_wave_barrier();   // A reads done before D overwrites s_pf

    #pragma unroll
    for (int t = 0; t < 4; t++) {
        v8s bh[4], bl[4];
        #pragma unroll
        for (int c = 0; c < 4; c++) {
            bh[c] = w2frag[((t * 4 + c) * 2 + 0) * 64 + j];
            bl[c] = w2frag[((t * 4 + c) * 2 + 1) * 64 + j];
        }
        v4f acc = {0.f, 0.f, 0.f, 0.f};
        #pragma unroll
        for (int c = 0; c < 4; c++) {
            acc = __builtin_amdgcn_mfma_f32_16x16x32_bf16(ah[c], bh[c], acc, 0, 0, 0);
            acc = __builtin_amdgcn_mfma_f32_16x16x32_bf16(al[c], bh[c], acc, 0, 0, 0);
            acc = __builtin_amdgcn_mfma_f32_16x16x32_bf16(ah[c], bl[c], acc, 0, 0, 0);
        }
        #pragma unroll
        for (int r = 0; r < 4; r++) s_pf[wslot][q * 4 + r][t * 16 + m] = acc[r];
    }
    __builtin_amdgcn_wave_barrier();

    const int first = rli(P.vx, 0), last = rli(P.vx, RUN - 1);
    const bool firstExt = (rli(P.vx, 17) == first);
    const bool lastExt  = (rli(P.vx, 16) == last);
    int vprev = first;
    float smax = -3.4e38f;
    for (int p = 0; p < RUN; p++) {
        int vp = rli(P.vx, p);
        if (vp != vprev) {
            float r = fmaxf(smax, 0.f);
            size_t o = (size_t)vprev * 64 + j;
            bool ua = (vprev == first && firstExt) || (vprev == last && lastExt);
            if (ua) atomicMax((int*)out + o, __float_as_int(r));
            else out[o] = r;
            vprev = vp; smax = -3.4e38f;
        }
        smax = fmaxf(smax, s_pf[wslot][p][j]);
    }
    {
        float r = fmaxf(smax, 0.f);
        size_t o = (size_t)vprev * 64 + j;
        bool ua = (vprev == first && firstExt) || (vprev == last && lastExt);
        if (ua) atomicMax((int*)out + o, __float_as_int(r));
        else out[o] = r;
    }
}

extern "C" void kernel_launch(void* const* d_in, const int* in_sizes, int n_in,
                              void* d_out, int out_size, void* d_ws, size_t ws_size,
                              hipStream_t stream) {
    const float* pts = (const float*)d_in[0];
    const float* W1  = (const float*)d_in[1];
    const float* W2  = (const float*)d_in[2];
    float* out = (float*)d_out;

    float4* vsum4  = (float4*)d_ws;                         // CANVAS float4
    float*  v1     = (float*)(vsum4 + CANVASc);             // CANVAS*64 (16B aligned)
    v8s*    w2frag = (v8s*)(v1 + (size_t)CANVASc * 64);     // 2048 v8s
    v8s*    w1frag = w2frag + 2048;                         // 512 v8s
    int*    ord    = (int*)(w1frag + 512);                  // NPTS
    int*    key    = ord + NPTS;                            // NPTS
    int*    cnt    = key + NPTS;                            // CANVAS
    int*    gcur   = cnt + CANVASc;                         // 1
    int*    cursor = gcur + 1;                              // CANVAS

    hipMemsetAsync(vsum4, 0, (size_t)CANVASc * 16, stream);
    hipMemsetAsync(cnt, 0, (size_t)(CANVASc + 1) * 4, stream);      // cnt + gcur
    hipMemsetAsync(d_out, 0, (size_t)out_size * sizeof(float), stream);

    int gpts = (NPTS + 255) / 256;
    int gvox = (CANVASc + 255) / 256;
    k_stats  <<<gpts, 256, 0, stream>>>(pts, cnt, key, vsum4);
    k_alloc  <<<gvox, 256, 0, stream>>>(cnt, cursor, gcur);
    k_scatter<<<gpts, 256, 0, stream>>>(key, cursor, ord);
    kW       <<<5, 256, 0, stream>>>(W1, W2, w1frag, w2frag);
    k_div    <<<gvox, 256, 0, stream>>>(cnt, vsum4);
    kA       <<<NRUNS / 4, 256, 0, stream>>>(ord, pts, vsum4, w1frag, v1);
    kB       <<<NRUNS / 4, 256, 0, stream>>>(ord, pts, vsum4, w1frag, w2frag, v1, out);
}

// Round 3
// 269.578 us; speedup vs baseline: 1.1522x; 1.1522x over previous
//
#include <hip/hip_runtime.h>

#define NXc 468
#define NYc 468
#define CANVASc (468 * 468)   // 219024
#define NPTS 400000
#define RUN 16
#define NRUNS (NPTS / RUN)    // 25000 exactly

#define PCMIN_X (-74.88f)
#define PCMIN_Y (-74.88f)
#define VOX_X 0.32f
#define VOX_Y 0.32f
#define OFF_X (-74.72f)
#define OFF_Y (-74.72f)
#define OFF_Z (1.0f)

typedef __attribute__((ext_vector_type(8))) short v8s;   // 8 bf16 (4 VGPRs)
typedef __attribute__((ext_vector_type(4))) float v4f;   // MFMA acc

static_assert(sizeof(__bf16) == 2, "bf16 must be 2 bytes");

__device__ __forceinline__ float rlf(float x, int p) {
    return __int_as_float(__builtin_amdgcn_readlane(__float_as_int(x), p));
}
__device__ __forceinline__ int rli(int x, int p) {
    return __builtin_amdgcn_readlane(x, p);
}

// Native bf16 split: hi = RNE(f), lo = RNE(f - hi).
// gfx950 lowers float->__bf16 fptrunc to v_cvt_pk_bf16_f32 (paired) — far
// fewer VALU insts than the manual add/shift RNE sequence.
__device__ __forceinline__ void split8(const float* f, v8s& h, v8s& l) {
    #pragma unroll
    for (int i = 0; i < 8; i += 2) {
        __bf16 h0 = (__bf16)f[i];
        __bf16 h1 = (__bf16)f[i + 1];
        h[i]     = __builtin_bit_cast(short, h0);
        h[i + 1] = __builtin_bit_cast(short, h1);
        float l0 = f[i]     - (float)h0;
        float l1 = f[i + 1] - (float)h1;
        l[i]     = __builtin_bit_cast(short, (__bf16)l0);
        l[i + 1] = __builtin_bit_cast(short, (__bf16)l1);
    }
}

__device__ __forceinline__ int voxel_cell(float x, float y, int& cx, int& cy) {
    cx = (int)floorf((x - PCMIN_X) / VOX_X);
    cy = (int)floorf((y - PCMIN_Y) / VOX_Y);
    cx = min(max(cx, 0), NXc - 1);
    cy = min(max(cy, 0), NYc - 1);
    return cy * NXc + cx;
}

// Pass 0: per-voxel counts + per-point voxel key (coalesced).
// NOTE (R1 post-mortem): do NOT fold the vsum here as scattered float
// atomics — 1.6M random 4B RMWs measured 78 µs @ 0.5% VALU. Sorted-order
// kA0 is ~3x cheaper.
__global__ __launch_bounds__(256) void k_stats(const float* __restrict__ pts,
                                               int* __restrict__ cnt,
                                               int* __restrict__ key) {
    int i = blockIdx.x * 256 + threadIdx.x;
    if (i >= NPTS) return;
    float x = pts[i * 5 + 0], y = pts[i * 5 + 1];
    int cx, cy;
    int fl = voxel_cell(x, y, cx, cy);
    key[i] = fl;
    atomicAdd(&cnt[fl], 1);
}

// Pass 1: exclusive-scan alloc -> cursor
__global__ __launch_bounds__(256) void k_alloc(const int* __restrict__ cnt,
                                               int* __restrict__ cursor,
                                               int* __restrict__ gcur) {
    int v = blockIdx.x * 256 + threadIdx.x;
    int lane = threadIdx.x & 63;
    int c = (v < CANVASc) ? cnt[v] : 0;
    int scan = c;
    #pragma unroll
    for (int off = 1; off < 64; off <<= 1) {
        int t = __shfl_up(scan, off, 64);
        if (lane >= off) scan += t;
    }
    int total = __shfl(scan, 63, 64);
    int base = 0;
    if (lane == 0 && total > 0) base = atomicAdd(gcur, total);
    base = __shfl(base, 0, 64);
    if (v < CANVASc) cursor[v] = base + scan - c;
}

// Pass 2: index-only scatter (4B random writes instead of 20B records)
__global__ __launch_bounds__(256) void k_scatter(const int* __restrict__ key,
                                                 int* __restrict__ cursor,
                                                 int* __restrict__ ord) {
    int i = blockIdx.x * 256 + threadIdx.x;
    if (i >= NPTS) return;
    int fl = key[i];
    int pos = atomicAdd(&cursor[fl], 1);
    ord[pos] = i;
}

// gather one point record (random 20B, pts is L2/L3-warm)
__device__ __forceinline__ void gather_pt(const float* __restrict__ pts, int pi,
                                          float4& A, float& e1) {
    const float* pp = pts + (size_t)pi * 5;
    __builtin_memcpy(&A, pp, 16);   // 4B-aligned dwordx4
    e1 = pp[4];
}

// kA0: per-voxel xyz sums from sorted order (gather via ord).
__global__ __launch_bounds__(256) void kA0(const int* __restrict__ ord,
                                           const float* __restrict__ pts,
                                           float4* __restrict__ vsum4) {
    int wave = blockIdx.x * 4 + (threadIdx.x >> 6);
    int j = threadIdx.x & 63;
    int base = wave * RUN;

    int idx = -1;
    if (j < RUN) idx = base + j;
    else if (j == 16) idx = (base + RUN < NPTS) ? base + RUN : -1;
    else if (j == 17) idx = base - 1;
    float4 A = make_float4(0.f, 0.f, 0.f, 0.f);
    int vx = -1;
    if (idx >= 0) {
        int pi = ord[idx];
        float e1d;
        gather_pt(pts, pi, A, e1d);
        int cx, cy;
        vx = voxel_cell(A.x, A.y, cx, cy);
    }

    const int first = rli(vx, 0), last = rli(vx, RUN - 1);
    const bool firstExt = (rli(vx, 17) == first);
    const bool lastExt  = (rli(vx, 16) == last);

    int vprev = first;
    float sx = 0.f, sy = 0.f, sz = 0.f;
    for (int p = 0; p < RUN; p++) {
        int vp = rli(vx, p);
        if (vp != vprev) {
            if (j == 0) {
                bool ua = (vprev == first && firstExt) || (vprev == last && lastExt);
                if (ua) {
                    float* s = (float*)&vsum4[vprev];
                    unsafeAtomicAdd(s + 0, sx);
                    unsafeAtomicAdd(s + 1, sy);
                    unsafeAtomicAdd(s + 2, sz);
                } else {
                    vsum4[vprev] = make_float4(sx, sy, sz, 0.f);
                }
            }
            vprev = vp; sx = sy = sz = 0.f;
        }
        sx += rlf(A.x, p); sy += rlf(A.y, p); sz += rlf(A.z, p);
    }
    if (j == 0) {
        bool ua = (vprev == first && firstExt) || (vprev == last && lastExt);
        if (ua) {
            float* s = (float*)&vsum4[vprev];
            unsafeAtomicAdd(s + 0, sx);
            unsafeAtomicAdd(s + 1, sy);
            unsafeAtomicAdd(s + 2, sz);
        } else {
            vsum4[vprev] = make_float4(sx, sy, sz, 0.f);
        }
    }
}

// k_div: vsum -> vmean in place
__global__ __launch_bounds__(256) void k_div(const int* __restrict__ cnt,
                                             float4* __restrict__ vsum4) {
    int v = blockIdx.x * 256 + threadIdx.x;
    if (v >= CANVASc) return;
    int c = cnt[v];
    float inv = (c > 0) ? 1.0f / (float)c : 0.f;
    float4 s = vsum4[v];
    vsum4[v] = make_float4(s.x * inv, s.y * inv, s.z * inv, 0.f);
}

// kW: bf16 hi/lo B-fragments for W2 (4 tiles x 4 K-chunks) and W1 (4 tiles,
// K=32 single chunk, rows >= 11 zero). B[k][n]: n=lane&15, k=c*32+(lane>>4)*8+i.
__global__ __launch_bounds__(256) void kW(const float* __restrict__ W1,
                                          const float* __restrict__ W2,
                                          v8s* __restrict__ w1frag,
                                          v8s* __restrict__ w2frag) {
    int tid = blockIdx.x * 256 + threadIdx.x;   // 1280 total
    if (tid < 1024) {
        int f = tid >> 6, lane = tid & 63;
        int t = f >> 2, c = f & 3;
        int q = lane >> 4, n = lane & 15;
        float v[8];
        #pragma unroll
        for (int i = 0; i < 8; i++) v[i] = W2[(c * 32 + q * 8 + i) * 64 + t * 16 + n];
        v8s h, l;
        split8(v, h, l);
        w2frag[(f * 2 + 0) * 64 + lane] = h;
        w2frag[(f * 2 + 1) * 64 + lane] = l;
    } else if (tid < 1280) {
        int f = (tid - 1024) >> 6, lane = (tid - 1024) & 63;
        int q = lane >> 4, n = lane & 15;
        float v[8];
        #pragma unroll
        for (int i = 0; i < 8; i++) {
            int k = q * 8 + i;
            v[i] = (k < 11) ? W1[k * 64 + f * 16 + n] : 0.f;
        }
        v8s h, l;
        split8(v, h, l);
        w1frag[(f * 2 + 0) * 64 + lane] = h;
        w1frag[(f * 2 + 1) * 64 + lane] = l;
    }
}

// Per-lane prep: lanes 0..15 gather point base+j + vmean; lanes 16/17 peek
// neighbor voxels for run-edge detection.
struct PtRegs {
    float4 A;
    float  e1, fcx, fcy, fcz;
    float  mx, my, mz;
    int    vx;
};
__device__ __forceinline__ PtRegs load_pt(const int* __restrict__ ord,
                                          const float* __restrict__ pts,
                                          const float4* __restrict__ vmean4,
                                          int base, int j) {
    PtRegs r;
    r.A = make_float4(0.f, 0.f, 0.f, 0.f);
    r.e1 = r.fcx = r.fcy = r.fcz = r.mx = r.my = r.mz = 0.f;
    r.vx = -1;
    int idx = -1;
    if (j < RUN) idx = base + j;
    else if (j == 16) idx = (base + RUN < NPTS) ? base + RUN : -1;
    else if (j == 17) idx = base - 1;
    if (idx >= 0) {
        int pi = ord[idx];
        float4 A; float e1;
        gather_pt(pts, pi, A, e1);
        int cx, cy;
        int vv = voxel_cell(A.x, A.y, cx, cy);
        r.vx = vv;
        if (j < RUN) {
            r.A = A;
            r.e1 = e1;
            r.fcx = A.x - (cx * VOX_X + OFF_X);
            r.fcy = A.y - (cy * VOX_Y + OFF_Y);
            r.fcz = A.z - OFF_Z;
            float4 m = vmean4[vv];
            r.mx = m.x; r.my = m.y; r.mz = m.z;
        }
    }
    return r;
}

#define PSTR 68   // LDS row stride (floats)

// Shared phase-1: features -> LDS rows -> MFMA (K=32, 12 mfma) -> relu(D) -> LDS.
// On return s_pf rows 0..15 hold relu'd pf1[p][0..63].
__device__ __forceinline__ void phase1_mfma(float (*s_pf)[PSTR], const PtRegs& P,
                                            const v8s* __restrict__ w1frag, int j) {
    if (j < RUN) {
        float* row = s_pf[j];
        row[0] = P.A.x; row[1] = P.A.y; row[2] = P.A.z; row[3] = P.A.w; row[4] = P.e1;
        row[5] = P.A.x - P.mx; row[6] = P.A.y - P.my; row[7] = P.A.z - P.mz;
        row[8] = P.fcx; row[9] = P.fcy; row[10] = P.fcz;
        #pragma unroll
        for (int t = 11; t < 16; t++) row[t] = 0.f;
    }
    __builtin_amdgcn_wave_barrier();

    const int m = j & 15, q = j >> 4;
    v8s fh = {0,0,0,0,0,0,0,0}, fl_ = {0,0,0,0,0,0,0,0};
    if (q < 2) {
        float f8[8];
        #pragma unroll
        for (int i = 0; i < 8; i++) f8[i] = s_pf[m][q * 8 + i];
        split8(f8, fh, fl_);
    }
    v4f d[4];
    #pragma unroll
    for (int t = 0; t < 4; t++) {
        v8s bh = w1frag[(t * 2 + 0) * 64 + j];
        v8s bl = w1frag[(t * 2 + 1) * 64 + j];
        v4f acc = {0.f, 0.f, 0.f, 0.f};
        acc = __builtin_amdgcn_mfma_f32_16x16x32_bf16(fh,  bh, acc, 0, 0, 0);
        acc = __builtin_amdgcn_mfma_f32_16x16x32_bf16(fl_, bh, acc, 0, 0, 0);
        acc = __builtin_amdgcn_mfma_f32_16x16x32_bf16(fh,  bl, acc, 0, 0, 0);
        d[t] = acc;
    }
    __builtin_amdgcn_wave_barrier();   // feature reads complete before overwrite
    #pragma unroll
    for (int t = 0; t < 4; t++)
        #pragma unroll
        for (int r = 0; r < 4; r++)
            s_pf[q * 4 + r][t * 16 + m] = fmaxf(d[t][r], 0.f);
    __builtin_amdgcn_wave_barrier();
}

// kA: v1 = segment_max(pf1) with edge-detected atomics.
__global__ __launch_bounds__(256) void kA(const int* __restrict__ ord,
                                          const float* __restrict__ pts,
                                          const float4* __restrict__ vmean4,
                                          const v8s* __restrict__ w1frag,
                                          float* __restrict__ v1) {
    __shared__ float s_pf[4][RUN][PSTR];
    int wslot = threadIdx.x >> 6;
    int wave = blockIdx.x * 4 + wslot;
    int j = threadIdx.x & 63;
    int base = wave * RUN;

    PtRegs P = load_pt(ord, pts, vmean4, base, j);
    phase1_mfma(s_pf[wslot], P, w1frag, j);

    const int first = rli(P.vx, 0), last = rli(P.vx, RUN - 1);
    const bool firstExt = (rli(P.vx, 17) == first);
    const bool lastExt  = (rli(P.vx, 16) == last);
    int vprev = first;
    float smax = 0.f;
    for (int p = 0; p < RUN; p++) {
        int vp = rli(P.vx, p);
        if (vp != vprev) {
            size_t o = (size_t)vprev * 64 + j;
            bool ua = (vprev == first && firstExt) || (vprev == last && lastExt);
            if (ua) atomicMax((int*)v1 + o, __float_as_int(smax));
            else v1[o] = smax;
            vprev = vp; smax = 0.f;
        }
        smax = fmaxf(smax, s_pf[wslot][p][j]);
    }
    {
        size_t o = (size_t)vprev * 64 + j;
        bool ua = (vprev == first && firstExt) || (vprev == last && lastExt);
        if (ua) atomicMax((int*)v1 + o, __float_as_int(smax));
        else v1[o] = smax;
    }
}

// kB: D[p][j] = [pf1[p], v1[vox(p)]] @ W2 via MFMA -> segment max -> out.
__global__ __launch_bounds__(256) void kB(const int* __restrict__ ord,
                                          const float* __restrict__ pts,
                                          const float4* __restrict__ vmean4,
                                          const v8s* __restrict__ w1frag,
                                          const v8s* __restrict__ w2frag,
                                          const float* __restrict__ v1,
                                          float* __restrict__ out) {
    __shared__ float s_pf[4][RUN][PSTR];
    int wslot = threadIdx.x >> 6;
    int wave = blockIdx.x * 4 + wslot;
    int j = threadIdx.x & 63;
    int base = wave * RUN;

    PtRegs P = load_pt(ord, pts, vmean4, base, j);
    phase1_mfma(s_pf[wslot], P, w1frag, j);

    const int m = j & 15, q = j >> 4;

    // A-frags: chunks 0,1 = pf1 rows (lane-distinct LDS reads)
    v8s ah[4], al[4];
    #pragma unroll
    for (int c = 0; c < 2; c++) {
        float f[8];
        #pragma unroll
        for (int i = 0; i < 8; i++) f[i] = s_pf[wslot][m][c * 32 + q * 8 + i];
        split8(f, ah[c], al[c]);
    }
    // chunks 2,3 = v1[vox(point m)] (segment-constant: rides inside the acc)
    int vx_m = __builtin_amdgcn_ds_bpermute(m << 2, P.vx);
    {
        const float* vr = v1 + (size_t)vx_m * 64 + q * 8;
        #pragma unroll
        for (int c = 2; c < 4; c++) {
            float f[8];
            #pragma unroll
            for (int i = 0; i < 8; i++) f[i] = vr[(c - 2) * 32 + i];
            split8(f, ah[c], al[c]);
        }
    }
    __builtin_amdgcn_wave_barrier();   // A reads done before D overwrites s_pf

    #pragma unroll
    for (int t = 0; t < 4; t++) {
        v8s bh[4], bl[4];
        #pragma unroll
        for (int c = 0; c < 4; c++) {
            bh[c] = w2frag[((t * 4 + c) * 2 + 0) * 64 + j];
            bl[c] = w2frag[((t * 4 + c) * 2 + 1) * 64 + j];
        }
        v4f acc = {0.f, 0.f, 0.f, 0.f};
        #pragma unroll
        for (int c = 0; c < 4; c++) {
            acc = __builtin_amdgcn_mfma_f32_16x16x32_bf16(ah[c], bh[c], acc, 0, 0, 0);
            acc = __builtin_amdgcn_mfma_f32_16x16x32_bf16(al[c], bh[c], acc, 0, 0, 0);
            acc = __builtin_amdgcn_mfma_f32_16x16x32_bf16(ah[c], bl[c], acc, 0, 0, 0);
        }
        #pragma unroll
        for (int r = 0; r < 4; r++) s_pf[wslot][q * 4 + r][t * 16 + m] = acc[r];
    }
    __builtin_amdgcn_wave_barrier();

    const int first = rli(P.vx, 0), last = rli(P.vx, RUN - 1);
    const bool firstExt = (rli(P.vx, 17) == first);
    const bool lastExt  = (rli(P.vx, 16) == last);
    int vprev = first;
    float smax = -3.4e38f;
    for (int p = 0; p < RUN; p++) {
        int vp = rli(P.vx, p);
        if (vp != vprev) {
            float r = fmaxf(smax, 0.f);
            size_t o = (size_t)vprev * 64 + j;
            bool ua = (vprev == first && firstExt) || (vprev == last && lastExt);
            if (ua) atomicMax((int*)out + o, __float_as_int(r));
            else out[o] = r;
            vprev = vp; smax = -3.4e38f;
        }
        smax = fmaxf(smax, s_pf[wslot][p][j]);
    }
    {
        float r = fmaxf(smax, 0.f);
        size_t o = (size_t)vprev * 64 + j;
        bool ua = (vprev == first && firstExt) || (vprev == last && lastExt);
        if (ua) atomicMax((int*)out + o, __float_as_int(r));
        else out[o] = r;
    }
}

extern "C" void kernel_launch(void* const* d_in, const int* in_sizes, int n_in,
                              void* d_out, int out_size, void* d_ws, size_t ws_size,
                              hipStream_t stream) {
    const float* pts = (const float*)d_in[0];
    const float* W1  = (const float*)d_in[1];
    const float* W2  = (const float*)d_in[2];
    float* out = (float*)d_out;

    float4* vsum4  = (float4*)d_ws;                         // CANVAS float4
    float*  v1     = (float*)(vsum4 + CANVASc);             // CANVAS*64 (16B aligned)
    v8s*    w2frag = (v8s*)(v1 + (size_t)CANVASc * 64);     // 2048 v8s
    v8s*    w1frag = w2frag + 2048;                         // 512 v8s
    int*    ord    = (int*)(w1frag + 512);                  // NPTS
    int*    key    = ord + NPTS;                            // NPTS
    int*    cnt    = key + NPTS;                            // CANVAS
    int*    gcur   = cnt + CANVASc;                         // 1
    int*    cursor = gcur + 1;                              // CANVAS

    hipMemsetAsync(vsum4, 0, (size_t)CANVASc * 16, stream);
    hipMemsetAsync(cnt, 0, (size_t)(CANVASc + 1) * 4, stream);      // cnt + gcur
    hipMemsetAsync(d_out, 0, (size_t)out_size * sizeof(float), stream);

    int gpts = (NPTS + 255) / 256;
    int gvox = (CANVASc + 255) / 256;
    k_stats  <<<gpts, 256, 0, stream>>>(pts, cnt, key);
    k_alloc  <<<gvox, 256, 0, stream>>>(cnt, cursor, gcur);
    k_scatter<<<gpts, 256, 0, stream>>>(key, cursor, ord);
    kW       <<<5, 256, 0, stream>>>(W1, W2, w1frag, w2frag);
    kA0      <<<NRUNS / 4, 256, 0, stream>>>(ord, pts, vsum4);
    k_div    <<<gvox, 256, 0, stream>>>(cnt, vsum4);
    kA       <<<NRUNS / 4, 256, 0, stream>>>(ord, pts, vsum4, w1frag, v1);
    kB       <<<NRUNS / 4, 256, 0, stream>>>(ord, pts, vsum4, w1frag, w2frag, v1, out);
}

// Round 4
// 246.781 us; speedup vs baseline: 1.2586x; 1.0924x over previous
//
#include <hip/hip_runtime.h>

#define NXc 468
#define NYc 468
#define CANVASc (468 * 468)   // 219024
#define NPTS 400000
#define RUN 16
#define NRUNS (NPTS / RUN)    // 25000 exactly

#define PCMIN_X (-74.88f)
#define PCMIN_Y (-74.88f)
#define VOX_X 0.32f
#define VOX_Y 0.32f
#define OFF_X (-74.72f)
#define OFF_Y (-74.72f)
#define OFF_Z (1.0f)

typedef __attribute__((ext_vector_type(8))) short v8s;   // 8 bf16 (4 VGPRs)
typedef __attribute__((ext_vector_type(4))) float v4f;   // MFMA acc

static_assert(sizeof(__bf16) == 2, "bf16 must be 2 bytes");

__device__ __forceinline__ int rli(int x, int p) {
    return __builtin_amdgcn_readlane(x, p);
}

// Native bf16 split: hi = RNE(f), lo = RNE(f - hi).
// R3 A/B: cut kB VALUBusy 37->26% (vs manual bit-twiddle RNE). Keep.
__device__ __forceinline__ void split8(const float* f, v8s& h, v8s& l) {
    #pragma unroll
    for (int i = 0; i < 8; i += 2) {
        __bf16 h0 = (__bf16)f[i];
        __bf16 h1 = (__bf16)f[i + 1];
        h[i]     = __builtin_bit_cast(short, h0);
        h[i + 1] = __builtin_bit_cast(short, h1);
        float l0 = f[i]     - (float)h0;
        float l1 = f[i + 1] - (float)h1;
        l[i]     = __builtin_bit_cast(short, (__bf16)l0);
        l[i + 1] = __builtin_bit_cast(short, (__bf16)l1);
    }
}

__device__ __forceinline__ int voxel_cell(float x, float y, int& cx, int& cy) {
    cx = (int)floorf((x - PCMIN_X) / VOX_X);
    cy = (int)floorf((y - PCMIN_Y) / VOX_Y);
    cx = min(max(cx, 0), NXc - 1);
    cy = min(max(cy, 0), NYc - 1);
    return cy * NXc + cx;
}

// Pass 0: per-voxel counts only.
// (R1 post-mortem: no scattered float atomics here — 1.6M random 4B RMWs
//  measured 78 µs.)
__global__ __launch_bounds__(256) void k_stats(const float* __restrict__ pts,
                                               int* __restrict__ cnt) {
    int i = blockIdx.x * 256 + threadIdx.x;
    if (i >= NPTS) return;
    float x = pts[i * 5 + 0], y = pts[i * 5 + 1];
    int cx, cy;
    int fl = voxel_cell(x, y, cx, cy);
    atomicAdd(&cnt[fl], 1);
}

// Pass 1: exclusive-scan alloc -> cursor
__global__ __launch_bounds__(256) void k_alloc(const int* __restrict__ cnt,
                                               int* __restrict__ cursor,
                                               int* __restrict__ gcur) {
    int v = blockIdx.x * 256 + threadIdx.x;
    int lane = threadIdx.x & 63;
    int c = (v < CANVASc) ? cnt[v] : 0;
    int scan = c;
    #pragma unroll
    for (int off = 1; off < 64; off <<= 1) {
        int t = __shfl_up(scan, off, 64);
        if (lane >= off) scan += t;
    }
    int total = __shfl(scan, 63, 64);
    int base = 0;
    if (lane == 0 && total > 0) base = atomicAdd(gcur, total);
    base = __shfl(base, 0, 64);
    if (v < CANVASc) cursor[v] = base + scan - c;
}

// gather one point record (random 20B, used only by k_scatter now)
__device__ __forceinline__ void gather_pt(const float* __restrict__ pts, int pi,
                                          float4& A, float& e1) {
    const float* pp = pts + (size_t)pi * 5;
    __builtin_memcpy(&A, pp, 16);   // 4B-aligned dwordx4
    e1 = pp[4];
}

// Pass 2: record scatter. Writes the FULL point record (x,y,z,e0 as float4
// + e1) to the sorted position. R3 post-mortem: kA/kB are latency-bound on
// the ord->pts dependent random-gather chain; paying scattered *stores*
// here (fire-and-forget, sorted positions re-fill L2 lines) buys
// zero-indirection coalesced reads in kV/kA/kB.
__global__ __launch_bounds__(256) void k_scatter(const float* __restrict__ pts,
                                                 int* __restrict__ cursor,
                                                 float4* __restrict__ pos4,
                                                 float* __restrict__ e1b) {
    int i = blockIdx.x * 256 + threadIdx.x;
    if (i >= NPTS) return;
    float4 A; float e1;
    gather_pt(pts, i, A, e1);
    int cx, cy;
    int fl = voxel_cell(A.x, A.y, cx, cy);
    int pos = atomicAdd(&cursor[fl], 1);
    pos4[pos] = A;
    e1b[pos] = e1;
}

// kV: one thread per voxel -> vmean directly (replaces kA0 + k_div).
// cnt[v] consecutive float4 reads (avg 1.8), no serial readlane chain.
__global__ __launch_bounds__(256) void kV(const int* __restrict__ cnt,
                                          const int* __restrict__ cursor,
                                          const float4* __restrict__ pos4,
                                          float4* __restrict__ vmean4) {
    int v = blockIdx.x * 256 + threadIdx.x;
    if (v >= CANVASc) return;
    int c = cnt[v];
    if (c == 0) return;                 // empty voxels never read downstream
    int start = cursor[v] - c;          // cursor is post-scatter = start + c
    float sx = 0.f, sy = 0.f, sz = 0.f;
    for (int i = 0; i < c; i++) {
        float4 p = pos4[start + i];
        sx += p.x; sy += p.y; sz += p.z;
    }
    float inv = 1.0f / (float)c;
    vmean4[v] = make_float4(sx * inv, sy * inv, sz * inv, 0.f);
}

// kW: bf16 hi/lo B-fragments for W2 (4 tiles x 4 K-chunks) and W1 (4 tiles,
// K=32 single chunk, rows >= 11 zero). B[k][n]: n=lane&15, k=c*32+(lane>>4)*8+i.
__global__ __launch_bounds__(256) void kW(const float* __restrict__ W1,
                                          const float* __restrict__ W2,
                                          v8s* __restrict__ w1frag,
                                          v8s* __restrict__ w2frag) {
    int tid = blockIdx.x * 256 + threadIdx.x;   // 1280 total
    if (tid < 1024) {
        int f = tid >> 6, lane = tid & 63;
        int t = f >> 2, c = f & 3;
        int q = lane >> 4, n = lane & 15;
        float v[8];
        #pragma unroll
        for (int i = 0; i < 8; i++) v[i] = W2[(c * 32 + q * 8 + i) * 64 + t * 16 + n];
        v8s h, l;
        split8(v, h, l);
        w2frag[(f * 2 + 0) * 64 + lane] = h;
        w2frag[(f * 2 + 1) * 64 + lane] = l;
    } else if (tid < 1280) {
        int f = (tid - 1024) >> 6, lane = (tid - 1024) & 63;
        int q = lane >> 4, n = lane & 15;
        float v[8];
        #pragma unroll
        for (int i = 0; i < 8; i++) {
            int k = q * 8 + i;
            v[i] = (k < 11) ? W1[k * 64 + f * 16 + n] : 0.f;
        }
        v8s h, l;
        split8(v, h, l);
        w1frag[(f * 2 + 0) * 64 + lane] = h;
        w1frag[(f * 2 + 1) * 64 + lane] = l;
    }
}

// Per-lane prep: lanes 0..15 read their sorted record (coalesced float4!)
// + vmean; lanes 16/17 peek neighbor records for run-edge detection.
struct PtRegs {
    float4 A;
    float  e1, fcx, fcy, fcz;
    float  mx, my, mz;
    int    vx;
};
__device__ __forceinline__ PtRegs load_pt(const float4* __restrict__ pos4,
                                          const float* __restrict__ e1b,
                                          const float4* __restrict__ vmean4,
                                          int base, int j) {
    PtRegs r;
    r.A = make_float4(0.f, 0.f, 0.f, 0.f);
    r.e1 = r.fcx = r.fcy = r.fcz = r.mx = r.my = r.mz = 0.f;
    r.vx = -1;
    int idx = -1;
    if (j < RUN) idx = base + j;
    else if (j == 16) idx = (base + RUN < NPTS) ? base + RUN : -1;
    else if (j == 17) idx = base - 1;
    if (idx >= 0) {
        float4 A = pos4[idx];
        int cx, cy;
        int vv = voxel_cell(A.x, A.y, cx, cy);
        r.vx = vv;
        if (j < RUN) {
            r.A = A;
            r.e1 = e1b[idx];
            r.fcx = A.x - (cx * VOX_X + OFF_X);
            r.fcy = A.y - (cy * VOX_Y + OFF_Y);
            r.fcz = A.z - OFF_Z;
            float4 m = vmean4[vv];
            r.mx = m.x; r.my = m.y; r.mz = m.z;
        }
    }
    return r;
}

#define PSTR 68   // LDS row stride (floats)

// Shared phase-1: features -> LDS rows -> MFMA (K=32, 12 mfma) -> relu(D) -> LDS.
// On return s_pf rows 0..15 hold relu'd pf1[p][0..63].
__device__ __forceinline__ void phase1_mfma(float (*s_pf)[PSTR], const PtRegs& P,
                                            const v8s* __restrict__ w1frag, int j) {
    if (j < RUN) {
        float* row = s_pf[j];
        row[0] = P.A.x; row[1] = P.A.y; row[2] = P.A.z; row[3] = P.A.w; row[4] = P.e1;
        row[5] = P.A.x - P.mx; row[6] = P.A.y - P.my; row[7] = P.A.z - P.mz;
        row[8] = P.fcx; row[9] = P.fcy; row[10] = P.fcz;
        #pragma unroll
        for (int t = 11; t < 16; t++) row[t] = 0.f;
    }
    __builtin_amdgcn_wave_barrier();

    const int m = j & 15, q = j >> 4;
    v8s fh = {0,0,0,0,0,0,0,0}, fl_ = {0,0,0,0,0,0,0,0};
    if (q < 2) {
        float f8[8];
        #pragma unroll
        for (int i = 0; i < 8; i++) f8[i] = s_pf[m][q * 8 + i];
        split8(f8, fh, fl_);
    }
    v4f d[4];
    #pragma unroll
    for (int t = 0; t < 4; t++) {
        v8s bh = w1frag[(t * 2 + 0) * 64 + j];
        v8s bl = w1frag[(t * 2 + 1) * 64 + j];
        v4f acc = {0.f, 0.f, 0.f, 0.f};
        acc = __builtin_amdgcn_mfma_f32_16x16x32_bf16(fh,  bh, acc, 0, 0, 0);
        acc = __builtin_amdgcn_mfma_f32_16x16x32_bf16(fl_, bh, acc, 0, 0, 0);
        acc = __builtin_amdgcn_mfma_f32_16x16x32_bf16(fh,  bl, acc, 0, 0, 0);
        d[t] = acc;
    }
    __builtin_amdgcn_wave_barrier();   // feature reads complete before overwrite
    #pragma unroll
    for (int t = 0; t < 4; t++)
        #pragma unroll
        for (int r = 0; r < 4; r++)
            s_pf[q * 4 + r][t * 16 + m] = fmaxf(d[t][r], 0.f);
    __builtin_amdgcn_wave_barrier();
}

// kA: v1 = segment_max(pf1) with edge-detected atomics.
__global__ __launch_bounds__(256) void kA(const float4* __restrict__ pos4,
                                          const float* __restrict__ e1b,
                                          const float4* __restrict__ vmean4,
                                          const v8s* __restrict__ w1frag,
                                          float* __restrict__ v1) {
    __shared__ float s_pf[4][RUN][PSTR];
    int wslot = threadIdx.x >> 6;
    int wave = blockIdx.x * 4 + wslot;
    int j = threadIdx.x & 63;
    int base = wave * RUN;

    PtRegs P = load_pt(pos4, e1b, vmean4, base, j);
    phase1_mfma(s_pf[wslot], P, w1frag, j);

    const int first = rli(P.vx, 0), last = rli(P.vx, RUN - 1);
    const bool firstExt = (rli(P.vx, 17) == first);
    const bool lastExt  = (rli(P.vx, 16) == last);
    int vprev = first;
    float smax = 0.f;
    for (int p = 0; p < RUN; p++) {
        int vp = rli(P.vx, p);
        if (vp != vprev) {
            size_t o = (size_t)vprev * 64 + j;
            bool ua = (vprev == first && firstExt) || (vprev == last && lastExt);
            if (ua) atomicMax((int*)v1 + o, __float_as_int(smax));
            else v1[o] = smax;
            vprev = vp; smax = 0.f;
        }
        smax = fmaxf(smax, s_pf[wslot][p][j]);
    }
    {
        size_t o = (size_t)vprev * 64 + j;
        bool ua = (vprev == first && firstExt) || (vprev == last && lastExt);
        if (ua) atomicMax((int*)v1 + o, __float_as_int(smax));
        else v1[o] = smax;
    }
}

// kB: D[p][j] = [pf1[p], v1[vox(p)]] @ W2 via MFMA -> segment max -> out.
__global__ __launch_bounds__(256) void kB(const float4* __restrict__ pos4,
                                          const float* __restrict__ e1b,
                                          const float4* __restrict__ vmean4,
                                          const v8s* __restrict__ w1frag,
                                          const v8s* __restrict__ w2frag,
                                          const float* __restrict__ v1,
                                          float* __restrict__ out) {
    __shared__ float s_pf[4][RUN][PSTR];
    int wslot = threadIdx.x >> 6;
    int wave = blockIdx.x * 4 + wslot;
    int j = threadIdx.x & 63;
    int base = wave * RUN;

    PtRegs P = load_pt(pos4, e1b, vmean4, base, j);
    phase1_mfma(s_pf[wslot], P, w1frag, j);

    const int m = j & 15, q = j >> 4;

    // A-frags: chunks 0,1 = pf1 rows (lane-distinct LDS reads)
    v8s ah[4], al[4];
    #pragma unroll
    for (int c = 0; c < 2; c++) {
        float f[8];
        #pragma unroll
        for (int i = 0; i < 8; i++) f[i] = s_pf[wslot][m][c * 32 + q * 8 + i];
        split8(f, ah[c], al[c]);
    }
    // chunks 2,3 = v1[vox(point m)] (segment-constant: rides inside the acc)
    int vx_m = __builtin_amdgcn_ds_bpermute(m << 2, P.vx);
    {
        const float* vr = v1 + (size_t)vx_m * 64 + q * 8;
        #pragma unroll
        for (int c = 2; c < 4; c++) {
            float f[8];
            #pragma unroll
            for (int i = 0; i < 8; i++) f[i] = vr[(c - 2) * 32 + i];
            split8(f, ah[c], al[c]);
        }
    }
    __builtin_amdgcn_wave_barrier();   // A reads done before D overwrites s_pf

    #pragma unroll
    for (int t = 0; t < 4; t++) {
        v8s bh[4], bl[4];
        #pragma unroll
        for (int c = 0; c < 4; c++) {
            bh[c] = w2frag[((t * 4 + c) * 2 + 0) * 64 + j];
            bl[c] = w2frag[((t * 4 + c) * 2 + 1) * 64 + j];
        }
        v4f acc = {0.f, 0.f, 0.f, 0.f};
        #pragma unroll
        for (int c = 0; c < 4; c++) {
            acc = __builtin_amdgcn_mfma_f32_16x16x32_bf16(ah[c], bh[c], acc, 0, 0, 0);
            acc = __builtin_amdgcn_mfma_f32_16x16x32_bf16(al[c], bh[c], acc, 0, 0, 0);
            acc = __builtin_amdgcn_mfma_f32_16x16x32_bf16(ah[c], bl[c], acc, 0, 0, 0);
        }
        #pragma unroll
        for (int r = 0; r < 4; r++) s_pf[wslot][q * 4 + r][t * 16 + m] = acc[r];
    }
    __builtin_amdgcn_wave_barrier();

    const int first = rli(P.vx, 0), last = rli(P.vx, RUN - 1);
    const bool firstExt = (rli(P.vx, 17) == first);
    const bool lastExt  = (rli(P.vx, 16) == last);
    int vprev = first;
    float smax = -3.4e38f;
    for (int p = 0; p < RUN; p++) {
        int vp = rli(P.vx, p);
        if (vp != vprev) {
            float r = fmaxf(smax, 0.f);
            size_t o = (size_t)vprev * 64 + j;
            bool ua = (vprev == first && firstExt) || (vprev == last && lastExt);
            if (ua) atomicMax((int*)out + o, __float_as_int(r));
            else out[o] = r;
            vprev = vp; smax = -3.4e38f;
        }
        smax = fmaxf(smax, s_pf[wslot][p][j]);
    }
    {
        float r = fmaxf(smax, 0.f);
        size_t o = (size_t)vprev * 64 + j;
        bool ua = (vprev == first && firstExt) || (vprev == last && lastExt);
        if (ua) atomicMax((int*)out + o, __float_as_int(r));
        else out[o] = r;
    }
}

extern "C" void kernel_launch(void* const* d_in, const int* in_sizes, int n_in,
                              void* d_out, int out_size, void* d_ws, size_t ws_size,
                              hipStream_t stream) {
    const float* pts = (const float*)d_in[0];
    const float* W1  = (const float*)d_in[1];
    const float* W2  = (const float*)d_in[2];
    float* out = (float*)d_out;

    float4* vmean4 = (float4*)d_ws;                         // CANVAS float4
    float*  v1     = (float*)(vmean4 + CANVASc);            // CANVAS*64
    float4* pos4   = (float4*)(v1 + (size_t)CANVASc * 64);  // NPTS float4
    float*  e1b    = (float*)(pos4 + NPTS);                 // NPTS
    v8s*    w2frag = (v8s*)(e1b + NPTS);                    // 2048 v8s
    v8s*    w1frag = w2frag + 2048;                         // 512 v8s
    int*    cnt    = (int*)(w1frag + 512);                  // CANVAS
    int*    gcur   = cnt + CANVASc;                         // 1
    int*    cursor = gcur + 1;                              // CANVAS

    hipMemsetAsync(cnt, 0, (size_t)(CANVASc + 1) * 4, stream);      // cnt + gcur
    hipMemsetAsync(d_out, 0, (size_t)out_size * sizeof(float), stream);

    int gpts = (NPTS + 255) / 256;
    int gvox = (CANVASc + 255) / 256;
    k_stats  <<<gpts, 256, 0, stream>>>(pts, cnt);
    k_alloc  <<<gvox, 256, 0, stream>>>(cnt, cursor, gcur);
    k_scatter<<<gpts, 256, 0, stream>>>(pts, cursor, pos4, e1b);
    kW       <<<5, 256, 0, stream>>>(W1, W2, w1frag, w2frag);
    kV       <<<gvox, 256, 0, stream>>>(cnt, cursor, pos4, vmean4);
    kA       <<<NRUNS / 4, 256, 0, stream>>>(pos4, e1b, vmean4, w1frag, v1);
    kB       <<<NRUNS / 4, 256, 0, stream>>>(pos4, e1b, vmean4, w1frag, w2frag, v1, out);
}

// Round 5
// 243.870 us; speedup vs baseline: 1.2737x; 1.0119x over previous
//
#include <hip/hip_runtime.h>

#define NXc 468
#define NYc 468
#define CANVASc (468 * 468)   // 219024
#define NPTS 400000
#define RUN 16
#define NRUNS (NPTS / RUN)    // 25000 exactly

#define PCMIN_X (-74.88f)
#define PCMIN_Y (-74.88f)
#define VOX_X 0.32f
#define VOX_Y 0.32f
#define OFF_X (-74.72f)
#define OFF_Y (-74.72f)
#define OFF_Z (1.0f)

typedef __attribute__((ext_vector_type(8))) short v8s;   // 8 bf16 (4 VGPRs)
typedef __attribute__((ext_vector_type(4))) float v4f;   // MFMA acc

static_assert(sizeof(__bf16) == 2, "bf16 must be 2 bytes");

__device__ __forceinline__ int rli(int x, int p) {
    return __builtin_amdgcn_readlane(x, p);
}

// Native bf16 split: hi = RNE(f), lo = RNE(f - hi).
// R3 A/B: cut kB VALUBusy 37->26% (vs manual bit-twiddle RNE). Keep.
__device__ __forceinline__ void split8(const float* f, v8s& h, v8s& l) {
    #pragma unroll
    for (int i = 0; i < 8; i += 2) {
        __bf16 h0 = (__bf16)f[i];
        __bf16 h1 = (__bf16)f[i + 1];
        h[i]     = __builtin_bit_cast(short, h0);
        h[i + 1] = __builtin_bit_cast(short, h1);
        float l0 = f[i]     - (float)h0;
        float l1 = f[i + 1] - (float)h1;
        l[i]     = __builtin_bit_cast(short, (__bf16)l0);
        l[i + 1] = __builtin_bit_cast(short, (__bf16)l1);
    }
}

__device__ __forceinline__ int voxel_cell(float x, float y, int& cx, int& cy) {
    cx = (int)floorf((x - PCMIN_X) / VOX_X);
    cy = (int)floorf((y - PCMIN_Y) / VOX_Y);
    cx = min(max(cx, 0), NXc - 1);
    cy = min(max(cy, 0), NYc - 1);
    return cy * NXc + cx;
}

// Pass 0: per-voxel counts only.
// (R1 post-mortem: no scattered float atomics here — 1.6M random 4B RMWs
//  measured 78 µs.)
__global__ __launch_bounds__(256) void k_stats(const float* __restrict__ pts,
                                               int* __restrict__ cnt) {
    int i = blockIdx.x * 256 + threadIdx.x;
    if (i >= NPTS) return;
    float x = pts[i * 5 + 0], y = pts[i * 5 + 1];
    int cx, cy;
    int fl = voxel_cell(x, y, cx, cy);
    atomicAdd(&cnt[fl], 1);
}

// Pass 1: exclusive-scan alloc -> cursor
__global__ __launch_bounds__(256) void k_alloc(const int* __restrict__ cnt,
                                               int* __restrict__ cursor,
                                               int* __restrict__ gcur) {
    int v = blockIdx.x * 256 + threadIdx.x;
    int lane = threadIdx.x & 63;
    int c = (v < CANVASc) ? cnt[v] : 0;
    int scan = c;
    #pragma unroll
    for (int off = 1; off < 64; off <<= 1) {
        int t = __shfl_up(scan, off, 64);
        if (lane >= off) scan += t;
    }
    int total = __shfl(scan, 63, 64);
    int base = 0;
    if (lane == 0 && total > 0) base = atomicAdd(gcur, total);
    base = __shfl(base, 0, 64);
    if (v < CANVASc) cursor[v] = base + scan - c;
}

// gather one point record (random 20B, used only by k_scatter now)
__device__ __forceinline__ void gather_pt(const float* __restrict__ pts, int pi,
                                          float4& A, float& e1) {
    const float* pp = pts + (size_t)pi * 5;
    __builtin_memcpy(&A, pp, 16);   // 4B-aligned dwordx4
    e1 = pp[4];
}

// Pass 2: record scatter (R3 win: coalesced zero-indirection reads downstream)
__global__ __launch_bounds__(256) void k_scatter(const float* __restrict__ pts,
                                                 int* __restrict__ cursor,
                                                 float4* __restrict__ pos4,
                                                 float* __restrict__ e1b) {
    int i = blockIdx.x * 256 + threadIdx.x;
    if (i >= NPTS) return;
    float4 A; float e1;
    gather_pt(pts, i, A, e1);
    int cx, cy;
    int fl = voxel_cell(A.x, A.y, cx, cy);
    int pos = atomicAdd(&cursor[fl], 1);
    pos4[pos] = A;
    e1b[pos] = e1;
}

// kV: one thread per voxel -> vmean (replaces kA0 + k_div). Also zeroes the
// out-row of EMPTY voxels (replaces part of the 56 MB d_out memset; occupied
// voxels' rows are fully written by kB).
__global__ __launch_bounds__(256) void kV(const int* __restrict__ cnt,
                                          const int* __restrict__ cursor,
                                          const float4* __restrict__ pos4,
                                          float4* __restrict__ vmean4,
                                          float4* __restrict__ out4) {
    int v = blockIdx.x * 256 + threadIdx.x;
    if (v >= CANVASc) return;
    int c = cnt[v];
    if (c == 0) {
        float4 z = make_float4(0.f, 0.f, 0.f, 0.f);
        float4* o = out4 + (size_t)v * 16;
        #pragma unroll
        for (int i = 0; i < 16; i++) o[i] = z;
        return;
    }
    int start = cursor[v] - c;          // cursor is post-scatter = start + c
    float sx = 0.f, sy = 0.f, sz = 0.f;
    for (int i = 0; i < c; i++) {
        float4 p = pos4[start + i];
        sx += p.x; sy += p.y; sz += p.z;
    }
    float inv = 1.0f / (float)c;
    vmean4[v] = make_float4(sx * inv, sy * inv, sz * inv, 0.f);
}

// k_seam: zero the v1/out rows of voxels split across a wave boundary —
// exactly the rows that only ever receive atomicMax (>=0 values) in kA/kB.
// ~0.5 * 25000 seams -> ~6 MB of writes vs the removed 56 MB memset.
__global__ __launch_bounds__(256) void k_seam(const float4* __restrict__ pos4,
                                              float4* __restrict__ v14,
                                              float4* __restrict__ out4) {
    int w = blockIdx.x * 256 + threadIdx.x;   // wave index 1..NRUNS-1
    if (w == 0 || w >= NRUNS) return;
    int b = w * RUN;
    float4 Pa = pos4[b - 1];
    float4 Pb = pos4[b];
    int cx, cy;
    int va = voxel_cell(Pa.x, Pa.y, cx, cy);
    int vb = voxel_cell(Pb.x, Pb.y, cx, cy);
    if (va != vb) return;
    float4 z = make_float4(0.f, 0.f, 0.f, 0.f);
    float4* o = out4 + (size_t)va * 16;
    float4* q = v14 + (size_t)va * 16;
    #pragma unroll
    for (int i = 0; i < 16; i++) { o[i] = z; q[i] = z; }
}

// kW: bf16 hi/lo B-fragments for W2 (4 tiles x 4 K-chunks) and W1 (4 tiles,
// K=32 single chunk, rows >= 11 zero). B[k][n]: n=lane&15, k=c*32+(lane>>4)*8+i.
__global__ __launch_bounds__(256) void kW(const float* __restrict__ W1,
                                          const float* __restrict__ W2,
                                          v8s* __restrict__ w1frag,
                                          v8s* __restrict__ w2frag) {
    int tid = blockIdx.x * 256 + threadIdx.x;   // 1280 total
    if (tid < 1024) {
        int f = tid >> 6, lane = tid & 63;
        int t = f >> 2, c = f & 3;
        int q = lane >> 4, n = lane & 15;
        float v[8];
        #pragma unroll
        for (int i = 0; i < 8; i++) v[i] = W2[(c * 32 + q * 8 + i) * 64 + t * 16 + n];
        v8s h, l;
        split8(v, h, l);
        w2frag[(f * 2 + 0) * 64 + lane] = h;
        w2frag[(f * 2 + 1) * 64 + lane] = l;
    } else if (tid < 1280) {
        int f = (tid - 1024) >> 6, lane = (tid - 1024) & 63;
        int q = lane >> 4, n = lane & 15;
        float v[8];
        #pragma unroll
        for (int i = 0; i < 8; i++) {
            int k = q * 8 + i;
            v[i] = (k < 11) ? W1[k * 64 + f * 16 + n] : 0.f;
        }
        v8s h, l;
        split8(v, h, l);
        w1frag[(f * 2 + 0) * 64 + lane] = h;
        w1frag[(f * 2 + 1) * 64 + lane] = l;
    }
}

// Per-lane prep: lanes 0..15 read their sorted record (coalesced float4)
// + vmean; lanes 16/17 peek neighbor records for run-edge detection.
struct PtRegs {
    float4 A;
    float  e1, fcx, fcy, fcz;
    float  mx, my, mz;
    int    vx;
};
__device__ __forceinline__ PtRegs load_pt(const float4* __restrict__ pos4,
                                          const float* __restrict__ e1b,
                                          const float4* __restrict__ vmean4,
                                          int base, int j) {
    PtRegs r;
    r.A = make_float4(0.f, 0.f, 0.f, 0.f);
    r.e1 = r.fcx = r.fcy = r.fcz = r.mx = r.my = r.mz = 0.f;
    r.vx = -1;
    int idx = -1;
    if (j < RUN) idx = base + j;
    else if (j == 16) idx = (base + RUN < NPTS) ? base + RUN : -1;
    else if (j == 17) idx = base - 1;
    if (idx >= 0) {
        float4 A = pos4[idx];
        int cx, cy;
        int vv = voxel_cell(A.x, A.y, cx, cy);
        r.vx = vv;
        if (j < RUN) {
            r.A = A;
            r.e1 = e1b[idx];
            r.fcx = A.x - (cx * VOX_X + OFF_X);
            r.fcy = A.y - (cy * VOX_Y + OFF_Y);
            r.fcz = A.z - OFF_Z;
            float4 m = vmean4[vv];
            r.mx = m.x; r.my = m.y; r.mz = m.z;
        }
    }
    return r;
}

#define PSTR 68   // LDS row stride (floats); 68 -> 2-way bank alias (free)

// Shared phase-1: features -> LDS rows -> MFMA (K=32, 12 mfma) -> relu(D) -> LDS.
// On return s_pf rows 0..15 hold relu'd pf1[p][0..63].
__device__ __forceinline__ void phase1_mfma(float (*s_pf)[PSTR], const PtRegs& P,
                                            const v8s* __restrict__ w1frag, int j) {
    if (j < RUN) {
        float* row = s_pf[j];
        row[0] = P.A.x; row[1] = P.A.y; row[2] = P.A.z; row[3] = P.A.w; row[4] = P.e1;
        row[5] = P.A.x - P.mx; row[6] = P.A.y - P.my; row[7] = P.A.z - P.mz;
        row[8] = P.fcx; row[9] = P.fcy; row[10] = P.fcz;
        #pragma unroll
        for (int t = 11; t < 16; t++) row[t] = 0.f;
    }
    __builtin_amdgcn_wave_barrier();

    const int m = j & 15, q = j >> 4;
    v8s fh = {0,0,0,0,0,0,0,0}, fl_ = {0,0,0,0,0,0,0,0};
    if (q < 2) {
        float f8[8];
        #pragma unroll
        for (int i = 0; i < 8; i++) f8[i] = s_pf[m][q * 8 + i];
        split8(f8, fh, fl_);
    }
    v4f d[4];
    #pragma unroll
    for (int t = 0; t < 4; t++) {
        v8s bh = w1frag[(t * 2 + 0) * 64 + j];
        v8s bl = w1frag[(t * 2 + 1) * 64 + j];
        v4f acc = {0.f, 0.f, 0.f, 0.f};
        acc = __builtin_amdgcn_mfma_f32_16x16x32_bf16(fh,  bh, acc, 0, 0, 0);
        acc = __builtin_amdgcn_mfma_f32_16x16x32_bf16(fl_, bh, acc, 0, 0, 0);
        acc = __builtin_amdgcn_mfma_f32_16x16x32_bf16(fh,  bl, acc, 0, 0, 0);
        d[t] = acc;
    }
    __builtin_amdgcn_wave_barrier();   // feature reads complete before overwrite
    #pragma unroll
    for (int t = 0; t < 4; t++)
        #pragma unroll
        for (int r = 0; r < 4; r++)
            s_pf[q * 4 + r][t * 16 + m] = fmaxf(d[t][r], 0.f);
    __builtin_amdgcn_wave_barrier();
}

// kA: v1 = segment_max(pf1) with edge-detected atomics.
__global__ __launch_bounds__(256) void kA(const float4* __restrict__ pos4,
                                          const float* __restrict__ e1b,
                                          const float4* __restrict__ vmean4,
                                          const v8s* __restrict__ w1frag,
                                          float* __restrict__ v1) {
    __shared__ float s_pf[4][RUN][PSTR];
    int wslot = threadIdx.x >> 6;
    int wave = blockIdx.x * 4 + wslot;
    int j = threadIdx.x & 63;
    int base = wave * RUN;

    PtRegs P = load_pt(pos4, e1b, vmean4, base, j);
    phase1_mfma(s_pf[wslot], P, w1frag, j);

    const int first = rli(P.vx, 0), last = rli(P.vx, RUN - 1);
    const bool firstExt = (rli(P.vx, 17) == first);
    const bool lastExt  = (rli(P.vx, 16) == last);
    int vprev = first;
    float smax = 0.f;
    for (int p = 0; p < RUN; p++) {
        int vp = rli(P.vx, p);
        if (vp != vprev) {
            size_t o = (size_t)vprev * 64 + j;
            bool ua = (vprev == first && firstExt) || (vprev == last && lastExt);
            if (ua) atomicMax((int*)v1 + o, __float_as_int(smax));
            else v1[o] = smax;
            vprev = vp; smax = 0.f;
        }
        smax = fmaxf(smax, s_pf[wslot][p][j]);
    }
    {
        size_t o = (size_t)vprev * 64 + j;
        bool ua = (vprev == first && firstExt) || (vprev == last && lastExt);
        if (ua) atomicMax((int*)v1 + o, __float_as_int(smax));
        else v1[o] = smax;
    }
}

// kB: D[p][j] = [pf1[p], v1[vox(p)]] @ W2 via MFMA -> segment max -> out.
// R4 post-mortem: v1 gather (L3, ~600cyc) was trapped AFTER phase1 by the
// wave_barriers -> hoisted the raw loads above phase1 so they overlap MFMA.
__global__ __launch_bounds__(256) void kB(const float4* __restrict__ pos4,
                                          const float* __restrict__ e1b,
                                          const float4* __restrict__ vmean4,
                                          const v8s* __restrict__ w1frag,
                                          const v8s* __restrict__ w2frag,
                                          const float* __restrict__ v1,
                                          float* __restrict__ out) {
    __shared__ float s_pf[4][RUN][PSTR];
    int wslot = threadIdx.x >> 6;
    int wave = blockIdx.x * 4 + wslot;
    int j = threadIdx.x & 63;
    int base = wave * RUN;

    PtRegs P = load_pt(pos4, e1b, vmean4, base, j);

    const int m = j & 15, q = j >> 4;

    // Hoisted: v1[vox(point m)] raw row loads (independent of phase1).
    int vx_m = __builtin_amdgcn_ds_bpermute(m << 2, P.vx);
    float vf[16];
    {
        const float* vr = v1 + (size_t)vx_m * 64 + q * 8;
        #pragma unroll
        for (int c = 0; c < 2; c++)
            #pragma unroll
            for (int i = 0; i < 8; i++) vf[c * 8 + i] = vr[c * 32 + i];
    }

    phase1_mfma(s_pf[wslot], P, w1frag, j);

    // A-frags: chunks 0,1 = pf1 rows (lane-distinct LDS reads)
    v8s ah[4], al[4];
    #pragma unroll
    for (int c = 0; c < 2; c++) {
        float f[8];
        #pragma unroll
        for (int i = 0; i < 8; i++) f[i] = s_pf[wslot][m][c * 32 + q * 8 + i];
        split8(f, ah[c], al[c]);
    }
    // chunks 2,3 = hoisted v1 row (segment-constant: rides inside the acc)
    split8(vf + 0, ah[2], al[2]);
    split8(vf + 8, ah[3], al[3]);
    __builtin_amdgcn_wave_barrier();   // A reads done before D overwrites s_pf

    #pragma unroll
    for (int t = 0; t < 4; t++) {
        v8s bh[4], bl[4];
        #pragma unroll
        for (int c = 0; c < 4; c++) {
            bh[c] = w2frag[((t * 4 + c) * 2 + 0) * 64 + j];
            bl[c] = w2frag[((t * 4 + c) * 2 + 1) * 64 + j];
        }
        v4f acc = {0.f, 0.f, 0.f, 0.f};
        #pragma unroll
        for (int c = 0; c < 4; c++) {
            acc = __builtin_amdgcn_mfma_f32_16x16x32_bf16(ah[c], bh[c], acc, 0, 0, 0);
            acc = __builtin_amdgcn_mfma_f32_16x16x32_bf16(al[c], bh[c], acc, 0, 0, 0);
            acc = __builtin_amdgcn_mfma_f32_16x16x32_bf16(ah[c], bl[c], acc, 0, 0, 0);
        }
        #pragma unroll
        for (int r = 0; r < 4; r++) s_pf[wslot][q * 4 + r][t * 16 + m] = acc[r];
    }
    __builtin_amdgcn_wave_barrier();

    const int first = rli(P.vx, 0), last = rli(P.vx, RUN - 1);
    const bool firstExt = (rli(P.vx, 17) == first);
    const bool lastExt  = (rli(P.vx, 16) == last);
    int vprev = first;
    float smax = -3.4e38f;
    for (int p = 0; p < RUN; p++) {
        int vp = rli(P.vx, p);
        if (vp != vprev) {
            float r = fmaxf(smax, 0.f);
            size_t o = (size_t)vprev * 64 + j;
            bool ua = (vprev == first && firstExt) || (vprev == last && lastExt);
            if (ua) atomicMax((int*)out + o, __float_as_int(r));
            else out[o] = r;
            vprev = vp; smax = -3.4e38f;
        }
        smax = fmaxf(smax, s_pf[wslot][p][j]);
    }
    {
        float r = fmaxf(smax, 0.f);
        size_t o = (size_t)vprev * 64 + j;
        bool ua = (vprev == first && firstExt) || (vprev == last && lastExt);
        if (ua) atomicMax((int*)out + o, __float_as_int(r));
        else out[o] = r;
    }
}

extern "C" void kernel_launch(void* const* d_in, const int* in_sizes, int n_in,
                              void* d_out, int out_size, void* d_ws, size_t ws_size,
                              hipStream_t stream) {
    const float* pts = (const float*)d_in[0];
    const float* W1  = (const float*)d_in[1];
    const float* W2  = (const float*)d_in[2];
    float* out = (float*)d_out;

    float4* vmean4 = (float4*)d_ws;                         // CANVAS float4
    float*  v1     = (float*)(vmean4 + CANVASc);            // CANVAS*64
    float4* pos4   = (float4*)(v1 + (size_t)CANVASc * 64);  // NPTS float4
    float*  e1b    = (float*)(pos4 + NPTS);                 // NPTS
    v8s*    w2frag = (v8s*)(e1b + NPTS);                    // 2048 v8s
    v8s*    w1frag = w2frag + 2048;                         // 512 v8s
    int*    cnt    = (int*)(w1frag + 512);                  // CANVAS
    int*    gcur   = cnt + CANVASc;                         // 1
    int*    cursor = gcur + 1;                              // CANVAS

    hipMemsetAsync(cnt, 0, (size_t)(CANVASc + 1) * 4, stream);      // cnt + gcur

    int gpts = (NPTS + 255) / 256;
    int gvox = (CANVASc + 255) / 256;
    int gseam = (NRUNS + 255) / 256;
    k_stats  <<<gpts, 256, 0, stream>>>(pts, cnt);
    k_alloc  <<<gvox, 256, 0, stream>>>(cnt, cursor, gcur);
    k_scatter<<<gpts, 256, 0, stream>>>(pts, cursor, pos4, e1b);
    kW       <<<5, 256, 0, stream>>>(W1, W2, w1frag, w2frag);
    kV       <<<gvox, 256, 0, stream>>>(cnt, cursor, pos4, vmean4, (float4*)out);
    k_seam   <<<gseam, 256, 0, stream>>>(pos4, (float4*)v1, (float4*)out);
    kA       <<<NRUNS / 4, 256, 0, stream>>>(pos4, e1b, vmean4, w1frag, v1);
    kB       <<<NRUNS / 4, 256, 0, stream>>>(pos4, e1b, vmean4, w1frag, w2frag, v1, out);
}

// Round 6
// 242.192 us; speedup vs baseline: 1.2825x; 1.0069x over previous
//
#include <hip/hip_runtime.h>

#define NXc 468
#define NYc 468
#define CANVASc (468 * 468)   // 219024
#define NPTS 400000
#define RUN 16
#define NRUNS (NPTS / RUN)    // 25000 exactly
#define GPTS ((NPTS + 255) / 256)      // 1563
#define GVOX ((CANVASc + 255) / 256)   // 856
#define GSEAM ((NRUNS + 255) / 256)    // 98

#define PCMIN_X (-74.88f)
#define PCMIN_Y (-74.88f)
#define VOX_X 0.32f
#define VOX_Y 0.32f
#define OFF_X (-74.72f)
#define OFF_Y (-74.72f)
#define OFF_Z (1.0f)

typedef __attribute__((ext_vector_type(8))) short v8s;   // 8 bf16 (4 VGPRs)
typedef __attribute__((ext_vector_type(4))) float v4f;   // MFMA acc

static_assert(sizeof(__bf16) == 2, "bf16 must be 2 bytes");

__device__ __forceinline__ int rli(int x, int p) {
    return __builtin_amdgcn_readlane(x, p);
}

// Native bf16 split: hi = RNE(f), lo = RNE(f - hi).
// R3 A/B: cut kB VALUBusy 37->26% (vs manual bit-twiddle RNE). Keep.
__device__ __forceinline__ void split8(const float* f, v8s& h, v8s& l) {
    #pragma unroll
    for (int i = 0; i < 8; i += 2) {
        __bf16 h0 = (__bf16)f[i];
        __bf16 h1 = (__bf16)f[i + 1];
        h[i]     = __builtin_bit_cast(short, h0);
        h[i + 1] = __builtin_bit_cast(short, h1);
        float l0 = f[i]     - (float)h0;
        float l1 = f[i + 1] - (float)h1;
        l[i]     = __builtin_bit_cast(short, (__bf16)l0);
        l[i + 1] = __builtin_bit_cast(short, (__bf16)l1);
    }
}

// Bins MUST stay bit-identical everywhere (fp32 division, no reciprocal).
__device__ __forceinline__ int voxel_cell(float x, float y, int& cx, int& cy) {
    cx = (int)floorf((x - PCMIN_X) / VOX_X);
    cy = (int)floorf((y - PCMIN_Y) / VOX_Y);
    cx = min(max(cx, 0), NXc - 1);
    cy = min(max(cy, 0), NYc - 1);
    return cy * NXc + cx;
}

// kW body: bf16 hi/lo B-fragments for W2 (4 tiles x 4 K-chunks) and W1
// (4 tiles, K=32, rows >= 11 zero). B[k][n]: n=lane&15, k=c*32+(lane>>4)*8+i.
__device__ __forceinline__ void kw_body(int tid,
                                        const float* __restrict__ W1,
                                        const float* __restrict__ W2,
                                        v8s* __restrict__ w1frag,
                                        v8s* __restrict__ w2frag) {
    if (tid < 1024) {
        int f = tid >> 6, lane = tid & 63;
        int t = f >> 2, c = f & 3;
        int q = lane >> 4, n = lane & 15;
        float v[8];
        #pragma unroll
        for (int i = 0; i < 8; i++) v[i] = W2[(c * 32 + q * 8 + i) * 64 + t * 16 + n];
        v8s h, l;
        split8(v, h, l);
        w2frag[(f * 2 + 0) * 64 + lane] = h;
        w2frag[(f * 2 + 1) * 64 + lane] = l;
    } else if (tid < 1280) {
        int f = (tid - 1024) >> 6, lane = (tid - 1024) & 63;
        int q = lane >> 4, n = lane & 15;
        float v[8];
        #pragma unroll
        for (int i = 0; i < 8; i++) {
            int k = q * 8 + i;
            v[i] = (k < 11) ? W1[k * 64 + f * 16 + n] : 0.f;
        }
        v8s h, l;
        split8(v, h, l);
        w1frag[(f * 2 + 0) * 64 + lane] = h;
        w1frag[(f * 2 + 1) * 64 + lane] = l;
    }
}

// Pass 0: per-voxel counts; tail blocks build W-fragments (dispatch merge).
// (R1 post-mortem: no scattered float atomics here — 78 µs lesson.)
__global__ __launch_bounds__(256) void k_stats(const float* __restrict__ pts,
                                               int* __restrict__ cnt,
                                               const float* __restrict__ W1,
                                               const float* __restrict__ W2,
                                               v8s* __restrict__ w1frag,
                                               v8s* __restrict__ w2frag) {
    int b = blockIdx.x;
    if (b >= GPTS) {
        kw_body((b - GPTS) * 256 + threadIdx.x, W1, W2, w1frag, w2frag);
        return;
    }
    int i = b * 256 + threadIdx.x;
    if (i >= NPTS) return;
    float x = pts[i * 5 + 0], y = pts[i * 5 + 1];
    int cx, cy;
    int fl = voxel_cell(x, y, cx, cy);
    atomicAdd(&cnt[fl], 1);
}

// Pass 1: exclusive-scan alloc -> cursor
__global__ __launch_bounds__(256) void k_alloc(const int* __restrict__ cnt,
                                               int* __restrict__ cursor,
                                               int* __restrict__ gcur) {
    int v = blockIdx.x * 256 + threadIdx.x;
    int lane = threadIdx.x & 63;
    int c = (v < CANVASc) ? cnt[v] : 0;
    int scan = c;
    #pragma unroll
    for (int off = 1; off < 64; off <<= 1) {
        int t = __shfl_up(scan, off, 64);
        if (lane >= off) scan += t;
    }
    int total = __shfl(scan, 63, 64);
    int base = 0;
    if (lane == 0 && total > 0) base = atomicAdd(gcur, total);
    base = __shfl(base, 0, 64);
    if (v < CANVASc) cursor[v] = base + scan - c;
}

// gather one point record (random 20B; only k_scatter pays this now)
__device__ __forceinline__ void gather_pt(const float* __restrict__ pts, int pi,
                                          float4& A, float& e1) {
    const float* pp = pts + (size_t)pi * 5;
    __builtin_memcpy(&A, pp, 16);   // 4B-aligned dwordx4
    e1 = pp[4];
}

// Pass 2: record scatter (R3 win) + packed cell (R5: removes the fp32-div
// voxel recompute from the dependent load chain in kA/kB/seam).
__global__ __launch_bounds__(256) void k_scatter(const float* __restrict__ pts,
                                                 int* __restrict__ cursor,
                                                 float4* __restrict__ pos4,
                                                 float* __restrict__ e1b,
                                                 int* __restrict__ cellb) {
    int i = blockIdx.x * 256 + threadIdx.x;
    if (i >= NPTS) return;
    float4 A; float e1;
    gather_pt(pts, i, A, e1);
    int cx, cy;
    int fl = voxel_cell(A.x, A.y, cx, cy);
    int pos = atomicAdd(&cursor[fl], 1);
    pos4[pos] = A;
    e1b[pos] = e1;
    cellb[pos] = cx | (cy << 16);
}

// kV: per-voxel vmean + empty-row out-zeroing; tail blocks zero the v1/out
// rows of seam voxels (the only rows that receive atomicMax) — dispatch merge.
__global__ __launch_bounds__(256) void kV(const int* __restrict__ cnt,
                                          const int* __restrict__ cursor,
                                          const float4* __restrict__ pos4,
                                          const int* __restrict__ cellb,
                                          float4* __restrict__ vmean4,
                                          float4* __restrict__ v14,
                                          float4* __restrict__ out4) {
    int b = blockIdx.x;
    if (b >= GVOX) {
        int w = (b - GVOX) * 256 + threadIdx.x;   // wave index
        if (w == 0 || w >= NRUNS) return;
        int bb = w * RUN;
        int ca = cellb[bb - 1], cb = cellb[bb];
        if (ca != cb) return;                     // no voxel spans this boundary
        int cx = ca & 0xFFFF, cy = ca >> 16;
        int va = cy * NXc + cx;
        float4 z = make_float4(0.f, 0.f, 0.f, 0.f);
        float4* o = out4 + (size_t)va * 16;
        float4* q = v14 + (size_t)va * 16;
        #pragma unroll
        for (int i = 0; i < 16; i++) { o[i] = z; q[i] = z; }
        return;
    }
    int v = b * 256 + threadIdx.x;
    if (v >= CANVASc) return;
    int c = cnt[v];
    if (c == 0) {
        float4 z = make_float4(0.f, 0.f, 0.f, 0.f);
        float4* o = out4 + (size_t)v * 16;
        #pragma unroll
        for (int i = 0; i < 16; i++) o[i] = z;
        return;
    }
    int start = cursor[v] - c;          // cursor is post-scatter = start + c
    float sx = 0.f, sy = 0.f, sz = 0.f;
    for (int i = 0; i < c; i++) {
        float4 p = pos4[start + i];
        sx += p.x; sy += p.y; sz += p.z;
    }
    float inv = 1.0f / (float)c;
    vmean4[v] = make_float4(sx * inv, sy * inv, sz * inv, 0.f);
}

// Per-lane prep: lanes 0..15 read their sorted record (coalesced float4)
// + packed cell + vmean; lanes 16/17 peek neighbor cells for edge detection.
struct PtRegs {
    float4 A;
    float  e1, fcx, fcy, fcz;
    float  mx, my, mz;
    int    vx;
};
__device__ __forceinline__ PtRegs load_pt(const float4* __restrict__ pos4,
                                          const float* __restrict__ e1b,
                                          const int* __restrict__ cellb,
                                          const float4* __restrict__ vmean4,
                                          int base, int j) {
    PtRegs r;
    r.A = make_float4(0.f, 0.f, 0.f, 0.f);
    r.e1 = r.fcx = r.fcy = r.fcz = r.mx = r.my = r.mz = 0.f;
    r.vx = -1;
    int idx = -1;
    if (j < RUN) idx = base + j;
    else if (j == 16) idx = (base + RUN < NPTS) ? base + RUN : -1;
    else if (j == 17) idx = base - 1;
    if (idx >= 0) {
        int cell = cellb[idx];
        int cx = cell & 0xFFFF, cy = cell >> 16;
        int vv = cy * NXc + cx;
        r.vx = vv;
        if (j < RUN) {
            float4 A = pos4[idx];
            r.A = A;
            r.e1 = e1b[idx];
            r.fcx = A.x - (cx * VOX_X + OFF_X);
            r.fcy = A.y - (cy * VOX_Y + OFF_Y);
            r.fcz = A.z - OFF_Z;
            float4 m = vmean4[vv];
            r.mx = m.x; r.my = m.y; r.mz = m.z;
        }
    }
    return r;
}

#define PSTR 68   // LDS row stride (floats); 68 -> 2-way bank alias (free)

// Shared phase-1: features -> LDS rows -> MFMA (K=32, 12 mfma) -> relu(D) -> LDS.
// On return s_pf rows 0..15 hold relu'd pf1[p][0..63].
__device__ __forceinline__ void phase1_mfma(float (*s_pf)[PSTR], const PtRegs& P,
                                            const v8s* __restrict__ w1frag, int j) {
    if (j < RUN) {
        float* row = s_pf[j];
        row[0] = P.A.x; row[1] = P.A.y; row[2] = P.A.z; row[3] = P.A.w; row[4] = P.e1;
        row[5] = P.A.x - P.mx; row[6] = P.A.y - P.my; row[7] = P.A.z - P.mz;
        row[8] = P.fcx; row[9] = P.fcy; row[10] = P.fcz;
        #pragma unroll
        for (int t = 11; t < 16; t++) row[t] = 0.f;
    }
    __builtin_amdgcn_wave_barrier();

    const int m = j & 15, q = j >> 4;
    v8s fh = {0,0,0,0,0,0,0,0}, fl_ = {0,0,0,0,0,0,0,0};
    if (q < 2) {
        float f8[8];
        #pragma unroll
        for (int i = 0; i < 8; i++) f8[i] = s_pf[m][q * 8 + i];
        split8(f8, fh, fl_);
    }
    v4f d[4];
    #pragma unroll
    for (int t = 0; t < 4; t++) {
        v8s bh = w1frag[(t * 2 + 0) * 64 + j];
        v8s bl = w1frag[(t * 2 + 1) * 64 + j];
        v4f acc = {0.f, 0.f, 0.f, 0.f};
        acc = __builtin_amdgcn_mfma_f32_16x16x32_bf16(fh,  bh, acc, 0, 0, 0);
        acc = __builtin_amdgcn_mfma_f32_16x16x32_bf16(fl_, bh, acc, 0, 0, 0);
        acc = __builtin_amdgcn_mfma_f32_16x16x32_bf16(fh,  bl, acc, 0, 0, 0);
        d[t] = acc;
    }
    __builtin_amdgcn_wave_barrier();   // feature reads complete before overwrite
    #pragma unroll
    for (int t = 0; t < 4; t++)
        #pragma unroll
        for (int r = 0; r < 4; r++)
            s_pf[q * 4 + r][t * 16 + m] = fmaxf(d[t][r], 0.f);
    __builtin_amdgcn_wave_barrier();
}

// kA: v1 = segment_max(pf1) with edge-detected atomics.
__global__ __launch_bounds__(256) void kA(const float4* __restrict__ pos4,
                                          const float* __restrict__ e1b,
                                          const int* __restrict__ cellb,
                                          const float4* __restrict__ vmean4,
                                          const v8s* __restrict__ w1frag,
                                          float* __restrict__ v1) {
    __shared__ float s_pf[4][RUN][PSTR];
    int wslot = threadIdx.x >> 6;
    int wave = blockIdx.x * 4 + wslot;
    int j = threadIdx.x & 63;
    int base = wave * RUN;

    PtRegs P = load_pt(pos4, e1b, cellb, vmean4, base, j);
    phase1_mfma(s_pf[wslot], P, w1frag, j);

    const int first = rli(P.vx, 0), last = rli(P.vx, RUN - 1);
    const bool firstExt = (rli(P.vx, 17) == first);
    const bool lastExt  = (rli(P.vx, 16) == last);
    int vprev = first;
    float smax = 0.f;
    for (int p = 0; p < RUN; p++) {
        int vp = rli(P.vx, p);
        if (vp != vprev) {
            size_t o = (size_t)vprev * 64 + j;
            bool ua = (vprev == first && firstExt) || (vprev == last && lastExt);
            if (ua) atomicMax((int*)v1 + o, __float_as_int(smax));
            else v1[o] = smax;
            vprev = vp; smax = 0.f;
        }
        smax = fmaxf(smax, s_pf[wslot][p][j]);
    }
    {
        size_t o = (size_t)vprev * 64 + j;
        bool ua = (vprev == first && firstExt) || (vprev == last && lastExt);
        if (ua) atomicMax((int*)v1 + o, __float_as_int(smax));
        else v1[o] = smax;
    }
}

// kB: D[p][j] = [pf1[p], v1[vox(p)]] @ W2 via MFMA -> segment max -> out.
// R4/R5: v1 row gather hoisted above phase1 (overlaps MFMA) — kept.
__global__ __launch_bounds__(256) void kB(const float4* __restrict__ pos4,
                                          const float* __restrict__ e1b,
                                          const int* __restrict__ cellb,
                                          const float4* __restrict__ vmean4,
                                          const v8s* __restrict__ w1frag,
                                          const v8s* __restrict__ w2frag,
                                          const float* __restrict__ v1,
                                          float* __restrict__ out) {
    __shared__ float s_pf[4][RUN][PSTR];
    int wslot = threadIdx.x >> 6;
    int wave = blockIdx.x * 4 + wslot;
    int j = threadIdx.x & 63;
    int base = wave * RUN;

    PtRegs P = load_pt(pos4, e1b, cellb, vmean4, base, j);

    const int m = j & 15, q = j >> 4;

    // Hoisted: v1[vox(point m)] raw row loads (independent of phase1).
    int vx_m = __builtin_amdgcn_ds_bpermute(m << 2, P.vx);
    float vf[16];
    {
        const float* vr = v1 + (size_t)vx_m * 64 + q * 8;
        #pragma unroll
        for (int c = 0; c < 2; c++)
            #pragma unroll
            for (int i = 0; i < 8; i++) vf[c * 8 + i] = vr[c * 32 + i];
    }

    phase1_mfma(s_pf[wslot], P, w1frag, j);

    // A-frags: chunks 0,1 = pf1 rows (lane-distinct LDS reads)
    v8s ah[4], al[4];
    #pragma unroll
    for (int c = 0; c < 2; c++) {
        float f[8];
        #pragma unroll
        for (int i = 0; i < 8; i++) f[i] = s_pf[wslot][m][c * 32 + q * 8 + i];
        split8(f, ah[c], al[c]);
    }
    // chunks 2,3 = hoisted v1 row (segment-constant: rides inside the acc)
    split8(vf + 0, ah[2], al[2]);
    split8(vf + 8, ah[3], al[3]);
    __builtin_amdgcn_wave_barrier();   // A reads done before D overwrites s_pf

    #pragma unroll
    for (int t = 0; t < 4; t++) {
        v8s bh[4], bl[4];
        #pragma unroll
        for (int c = 0; c < 4; c++) {
            bh[c] = w2frag[((t * 4 + c) * 2 + 0) * 64 + j];
            bl[c] = w2frag[((t * 4 + c) * 2 + 1) * 64 + j];
        }
        v4f acc = {0.f, 0.f, 0.f, 0.f};
        #pragma unroll
        for (int c = 0; c < 4; c++) {
            acc = __builtin_amdgcn_mfma_f32_16x16x32_bf16(ah[c], bh[c], acc, 0, 0, 0);
            acc = __builtin_amdgcn_mfma_f32_16x16x32_bf16(al[c], bh[c], acc, 0, 0, 0);
            acc = __builtin_amdgcn_mfma_f32_16x16x32_bf16(ah[c], bl[c], acc, 0, 0, 0);
        }
        #pragma unroll
        for (int r = 0; r < 4; r++) s_pf[wslot][q * 4 + r][t * 16 + m] = acc[r];
    }
    __builtin_amdgcn_wave_barrier();

    const int first = rli(P.vx, 0), last = rli(P.vx, RUN - 1);
    const bool firstExt = (rli(P.vx, 17) == first);
    const bool lastExt  = (rli(P.vx, 16) == last);
    int vprev = first;
    float smax = -3.4e38f;
    for (int p = 0; p < RUN; p++) {
        int vp = rli(P.vx, p);
        if (vp != vprev) {
            float r = fmaxf(smax, 0.f);
            size_t o = (size_t)vprev * 64 + j;
            bool ua = (vprev == first && firstExt) || (vprev == last && lastExt);
            if (ua) atomicMax((int*)out + o, __float_as_int(r));
            else out[o] = r;
            vprev = vp; smax = -3.4e38f;
        }
        smax = fmaxf(smax, s_pf[wslot][p][j]);
    }
    {
        float r = fmaxf(smax, 0.f);
        size_t o = (size_t)vprev * 64 + j;
        bool ua = (vprev == first && firstExt) || (vprev == last && lastExt);
        if (ua) atomicMax((int*)out + o, __float_as_int(r));
        else out[o] = r;
    }
}

extern "C" void kernel_launch(void* const* d_in, const int* in_sizes, int n_in,
                              void* d_out, int out_size, void* d_ws, size_t ws_size,
                              hipStream_t stream) {
    const float* pts = (const float*)d_in[0];
    const float* W1  = (const float*)d_in[1];
    const float* W2  = (const float*)d_in[2];
    float* out = (float*)d_out;

    float4* vmean4 = (float4*)d_ws;                         // CANVAS float4
    float*  v1     = (float*)(vmean4 + CANVASc);            // CANVAS*64
    float4* pos4   = (float4*)(v1 + (size_t)CANVASc * 64);  // NPTS float4
    float*  e1b    = (float*)(pos4 + NPTS);                 // NPTS
    int*    cellb  = (int*)(e1b + NPTS);                    // NPTS
    v8s*    w2frag = (v8s*)(cellb + NPTS);                  // 2048 v8s
    v8s*    w1frag = w2frag + 2048;                         // 512 v8s
    int*    cnt    = (int*)(w1frag + 512);                  // CANVAS
    int*    gcur   = cnt + CANVASc;                         // 1
    int*    cursor = gcur + 1;                              // CANVAS

    hipMemsetAsync(cnt, 0, (size_t)(CANVASc + 1) * 4, stream);      // cnt + gcur

    k_stats  <<<GPTS + 5, 256, 0, stream>>>(pts, cnt, W1, W2, w1frag, w2frag);
    k_alloc  <<<GVOX, 256, 0, stream>>>(cnt, cursor, gcur);
    k_scatter<<<GPTS, 256, 0, stream>>>(pts, cursor, pos4, e1b, cellb);
    kV       <<<GVOX + GSEAM, 256, 0, stream>>>(cnt, cursor, pos4, cellb,
                                                vmean4, (float4*)v1, (float4*)out);
    kA       <<<NRUNS / 4, 256, 0, stream>>>(pos4, e1b, cellb, vmean4, w1frag, v1);
    kB       <<<NRUNS / 4, 256, 0, stream>>>(pos4, e1b, cellb, vmean4, w1frag,
                                             w2frag, v1, out);
}

// Round 7
// 236.580 us; speedup vs baseline: 1.3129x; 1.0237x over previous
//
#include <hip/hip_runtime.h>

#define NXc 468
#define NYc 468
#define CANVASc (468 * 468)   // 219024
#define NPTS 400000
#define RUN 16
#define NRUNS (NPTS / RUN)    // 25000 exactly
#define GPTS ((NPTS + 255) / 256)      // 1563
#define GVOX ((CANVASc + 255) / 256)   // 856
#define GSEAM ((NRUNS + 255) / 256)    // 98

#define PCMIN_X (-74.88f)
#define PCMIN_Y (-74.88f)
#define VOX_X 0.32f
#define VOX_Y 0.32f
#define OFF_X (-74.72f)
#define OFF_Y (-74.72f)
#define OFF_Z (1.0f)

typedef __attribute__((ext_vector_type(8))) short v8s;   // 8 bf16 (4 VGPRs)
typedef __attribute__((ext_vector_type(4))) float v4f;   // MFMA acc

static_assert(sizeof(__bf16) == 2, "bf16 must be 2 bytes");

__device__ __forceinline__ int rli(int x, int p) {
    return __builtin_amdgcn_readlane(x, p);
}

// Native bf16 split: hi = RNE(f), lo = RNE(f - hi).
// R3 A/B: cut kB VALUBusy 37->26% (vs manual bit-twiddle RNE). Keep.
__device__ __forceinline__ void split8(const float* f, v8s& h, v8s& l) {
    #pragma unroll
    for (int i = 0; i < 8; i += 2) {
        __bf16 h0 = (__bf16)f[i];
        __bf16 h1 = (__bf16)f[i + 1];
        h[i]     = __builtin_bit_cast(short, h0);
        h[i + 1] = __builtin_bit_cast(short, h1);
        float l0 = f[i]     - (float)h0;
        float l1 = f[i + 1] - (float)h1;
        l[i]     = __builtin_bit_cast(short, (__bf16)l0);
        l[i + 1] = __builtin_bit_cast(short, (__bf16)l1);
    }
}

// Bins MUST stay bit-identical everywhere (fp32 division, no reciprocal).
__device__ __forceinline__ int voxel_cell(float x, float y, int& cx, int& cy) {
    cx = (int)floorf((x - PCMIN_X) / VOX_X);
    cy = (int)floorf((y - PCMIN_Y) / VOX_Y);
    cx = min(max(cx, 0), NXc - 1);
    cy = min(max(cy, 0), NYc - 1);
    return cy * NXc + cx;
}

// kW body: bf16 hi/lo B-fragments for W2 (4 tiles x 4 K-chunks) and W1
// (4 tiles, K=32, rows >= 11 zero). B[k][n]: n=lane&15, k=c*32+(lane>>4)*8+i.
__device__ __forceinline__ void kw_body(int tid,
                                        const float* __restrict__ W1,
                                        const float* __restrict__ W2,
                                        v8s* __restrict__ w1frag,
                                        v8s* __restrict__ w2frag) {
    if (tid < 1024) {
        int f = tid >> 6, lane = tid & 63;
        int t = f >> 2, c = f & 3;
        int q = lane >> 4, n = lane & 15;
        float v[8];
        #pragma unroll
        for (int i = 0; i < 8; i++) v[i] = W2[(c * 32 + q * 8 + i) * 64 + t * 16 + n];
        v8s h, l;
        split8(v, h, l);
        w2frag[(f * 2 + 0) * 64 + lane] = h;
        w2frag[(f * 2 + 1) * 64 + lane] = l;
    } else if (tid < 1280) {
        int f = (tid - 1024) >> 6, lane = (tid - 1024) & 63;
        int q = lane >> 4, n = lane & 15;
        float v[8];
        #pragma unroll
        for (int i = 0; i < 8; i++) {
            int k = q * 8 + i;
            v[i] = (k < 11) ? W1[k * 64 + f * 16 + n] : 0.f;
        }
        v8s h, l;
        split8(v, h, l);
        w1frag[(f * 2 + 0) * 64 + lane] = h;
        w1frag[(f * 2 + 1) * 64 + lane] = l;
    }
}

// Pass 0: per-voxel counts; tail blocks build W-fragments (dispatch merge).
__global__ __launch_bounds__(256) void k_stats(const float* __restrict__ pts,
                                               int* __restrict__ cnt,
                                               const float* __restrict__ W1,
                                               const float* __restrict__ W2,
                                               v8s* __restrict__ w1frag,
                                               v8s* __restrict__ w2frag) {
    int b = blockIdx.x;
    if (b >= GPTS) {
        kw_body((b - GPTS) * 256 + threadIdx.x, W1, W2, w1frag, w2frag);
        return;
    }
    int i = b * 256 + threadIdx.x;
    if (i >= NPTS) return;
    float x = pts[i * 5 + 0], y = pts[i * 5 + 1];
    int cx, cy;
    int fl = voxel_cell(x, y, cx, cy);
    atomicAdd(&cnt[fl], 1);
}

// Pass 1: exclusive-scan alloc -> cursor
__global__ __launch_bounds__(256) void k_alloc(const int* __restrict__ cnt,
                                               int* __restrict__ cursor,
                                               int* __restrict__ gcur) {
    int v = blockIdx.x * 256 + threadIdx.x;
    int lane = threadIdx.x & 63;
    int c = (v < CANVASc) ? cnt[v] : 0;
    int scan = c;
    #pragma unroll
    for (int off = 1; off < 64; off <<= 1) {
        int t = __shfl_up(scan, off, 64);
        if (lane >= off) scan += t;
    }
    int total = __shfl(scan, 63, 64);
    int base = 0;
    if (lane == 0 && total > 0) base = atomicAdd(gcur, total);
    base = __shfl(base, 0, 64);
    if (v < CANVASc) cursor[v] = base + scan - c;
}

// gather one point record (random 20B; only k_scatter pays this now)
__device__ __forceinline__ void gather_pt(const float* __restrict__ pts, int pi,
                                          float4& A, float& e1) {
    const float* pp = pts + (size_t)pi * 5;
    __builtin_memcpy(&A, pp, 16);   // 4B-aligned dwordx4
    e1 = pp[4];
}

// Pass 2: record scatter (R3 win) + packed cell.
__global__ __launch_bounds__(256) void k_scatter(const float* __restrict__ pts,
                                                 int* __restrict__ cursor,
                                                 float4* __restrict__ pos4,
                                                 float* __restrict__ e1b,
                                                 int* __restrict__ cellb) {
    int i = blockIdx.x * 256 + threadIdx.x;
    if (i >= NPTS) return;
    float4 A; float e1;
    gather_pt(pts, i, A, e1);
    int cx, cy;
    int fl = voxel_cell(A.x, A.y, cx, cy);
    int pos = atomicAdd(&cursor[fl], 1);
    pos4[pos] = A;
    e1b[pos] = e1;
    cellb[pos] = cx | (cy << 16);
}

// kV: per-voxel vmean + empty-row out-zeroing; tail blocks zero the v1/out
// rows of seam voxels (the only rows that receive atomicMax).
__global__ __launch_bounds__(256) void kV(const int* __restrict__ cnt,
                                          const int* __restrict__ cursor,
                                          const float4* __restrict__ pos4,
                                          const int* __restrict__ cellb,
                                          float4* __restrict__ vmean4,
                                          float4* __restrict__ v14,
                                          float4* __restrict__ out4) {
    int b = blockIdx.x;
    if (b >= GVOX) {
        int w = (b - GVOX) * 256 + threadIdx.x;   // wave index
        if (w == 0 || w >= NRUNS) return;
        int bb = w * RUN;
        int ca = cellb[bb - 1], cb = cellb[bb];
        if (ca != cb) return;                     // no voxel spans this boundary
        int cx = ca & 0xFFFF, cy = ca >> 16;
        int va = cy * NXc + cx;
        float4 z = make_float4(0.f, 0.f, 0.f, 0.f);
        float4* o = out4 + (size_t)va * 16;
        float4* q = v14 + (size_t)va * 16;
        #pragma unroll
        for (int i = 0; i < 16; i++) { o[i] = z; q[i] = z; }
        return;
    }
    int v = b * 256 + threadIdx.x;
    if (v >= CANVASc) return;
    int c = cnt[v];
    if (c == 0) {
        float4 z = make_float4(0.f, 0.f, 0.f, 0.f);
        float4* o = out4 + (size_t)v * 16;
        #pragma unroll
        for (int i = 0; i < 16; i++) o[i] = z;
        return;
    }
    int start = cursor[v] - c;          // cursor is post-scatter = start + c
    float sx = 0.f, sy = 0.f, sz = 0.f;
    for (int i = 0; i < c; i++) {
        float4 p = pos4[start + i];
        sx += p.x; sy += p.y; sz += p.z;
    }
    float inv = 1.0f / (float)c;
    vmean4[v] = make_float4(sx * inv, sy * inv, sz * inv, 0.f);
}

// Per-lane prep: lanes 0..15 read their sorted record (coalesced float4)
// + packed cell + vmean; lanes 16/17 peek neighbor cells for edge detection.
struct PtRegs {
    float4 A;
    float  e1, fcx, fcy, fcz;
    float  mx, my, mz;
    int    vx;
};
__device__ __forceinline__ PtRegs load_pt(const float4* __restrict__ pos4,
                                          const float* __restrict__ e1b,
                                          const int* __restrict__ cellb,
                                          const float4* __restrict__ vmean4,
                                          int base, int j) {
    PtRegs r;
    r.A = make_float4(0.f, 0.f, 0.f, 0.f);
    r.e1 = r.fcx = r.fcy = r.fcz = r.mx = r.my = r.mz = 0.f;
    r.vx = -1;
    int idx = -1;
    if (j < RUN) idx = base + j;
    else if (j == 16) idx = (base + RUN < NPTS) ? base + RUN : -1;
    else if (j == 17) idx = base - 1;
    if (idx >= 0) {
        int cell = cellb[idx];
        int cx = cell & 0xFFFF, cy = cell >> 16;
        int vv = cy * NXc + cx;
        r.vx = vv;
        if (j < RUN) {
            float4 A = pos4[idx];
            r.A = A;
            r.e1 = e1b[idx];
            r.fcx = A.x - (cx * VOX_X + OFF_X);
            r.fcy = A.y - (cy * VOX_Y + OFF_Y);
            r.fcz = A.z - OFF_Z;
            float4 m = vmean4[vv];
            r.mx = m.x; r.my = m.y; r.mz = m.z;
        }
    }
    return r;
}

#define PSTR 68   // LDS row stride (floats); 68 -> 2-way bank alias (free)

// Shared phase-1: features -> LDS rows -> MFMA (K=32, 12 mfma) -> relu(D) -> LDS.
// On return s_pf rows 0..15 hold relu'd pf1[p][0..63].
__device__ __forceinline__ void phase1_mfma(float (*s_pf)[PSTR], const PtRegs& P,
                                            const v8s* __restrict__ w1frag, int j) {
    if (j < RUN) {
        float* row = s_pf[j];
        row[0] = P.A.x; row[1] = P.A.y; row[2] = P.A.z; row[3] = P.A.w; row[4] = P.e1;
        row[5] = P.A.x - P.mx; row[6] = P.A.y - P.my; row[7] = P.A.z - P.mz;
        row[8] = P.fcx; row[9] = P.fcy; row[10] = P.fcz;
        #pragma unroll
        for (int t = 11; t < 16; t++) row[t] = 0.f;
    }
    __builtin_amdgcn_wave_barrier();

    const int m = j & 15, q = j >> 4;
    v8s fh = {0,0,0,0,0,0,0,0}, fl_ = {0,0,0,0,0,0,0,0};
    if (q < 2) {
        float f8[8];
        #pragma unroll
        for (int i = 0; i < 8; i++) f8[i] = s_pf[m][q * 8 + i];
        split8(f8, fh, fl_);
    }
    v4f d[4];
    #pragma unroll
    for (int t = 0; t < 4; t++) {
        v8s bh = w1frag[(t * 2 + 0) * 64 + j];
        v8s bl = w1frag[(t * 2 + 1) * 64 + j];
        v4f acc = {0.f, 0.f, 0.f, 0.f};
        acc = __builtin_amdgcn_mfma_f32_16x16x32_bf16(fh,  bh, acc, 0, 0, 0);
        acc = __builtin_amdgcn_mfma_f32_16x16x32_bf16(fl_, bh, acc, 0, 0, 0);
        acc = __builtin_amdgcn_mfma_f32_16x16x32_bf16(fh,  bl, acc, 0, 0, 0);
        d[t] = acc;
    }
    __builtin_amdgcn_wave_barrier();   // feature reads complete before overwrite
    #pragma unroll
    for (int t = 0; t < 4; t++)
        #pragma unroll
        for (int r = 0; r < 4; r++)
            s_pf[q * 4 + r][t * 16 + m] = fmaxf(d[t][r], 0.f);
    __builtin_amdgcn_wave_barrier();
}

// kA-lite (R6): v1 is only needed globally for SEAM voxels — interior voxels
// are recomputed locally in kB from its own pf1. Waves with no seam exit
// before phase1; seam waves write only their 1-2 seam rows via atomicMax.
__global__ __launch_bounds__(256) void kA(const float4* __restrict__ pos4,
                                          const float* __restrict__ e1b,
                                          const int* __restrict__ cellb,
                                          const float4* __restrict__ vmean4,
                                          const v8s* __restrict__ w1frag,
                                          float* __restrict__ v1) {
    __shared__ float s_pf[4][RUN][PSTR];
    int wslot = threadIdx.x >> 6;
    int wave = blockIdx.x * 4 + wslot;
    int j = threadIdx.x & 63;
    int base = wave * RUN;

    PtRegs P = load_pt(pos4, e1b, cellb, vmean4, base, j);

    const int first = rli(P.vx, 0), last = rli(P.vx, RUN - 1);
    const bool firstExt = (rli(P.vx, 17) == first);
    const bool lastExt  = (rli(P.vx, 16) == last);
    if (!firstExt && !lastExt) return;           // ~30% of waves: no seam

    phase1_mfma(s_pf[wslot], P, w1frag, j);

    int vprev = first;
    float smax = 0.f;
    for (int p = 0; p < RUN; p++) {
        int vp = rli(P.vx, p);
        if (vp != vprev) {
            bool ua = (vprev == first && firstExt) || (vprev == last && lastExt);
            if (ua) atomicMax((int*)v1 + (size_t)vprev * 64 + j, __float_as_int(smax));
            vprev = vp; smax = 0.f;
        }
        smax = fmaxf(smax, s_pf[wslot][p][j]);
    }
    {
        bool ua = (vprev == first && firstExt) || (vprev == last && lastExt);
        if (ua) atomicMax((int*)v1 + (size_t)vprev * 64 + j, __float_as_int(smax));
    }
}

// kB: D[p][j] = [pf1[p], v1[vox(p)]] @ W2 via MFMA -> segment max -> out.
// R6: interior lanes rebuild v1 locally from s_pf (ballot segment bounds +
// LDS fmax loop); only ext lanes read the global seam row.
__global__ __launch_bounds__(256) void kB(const float4* __restrict__ pos4,
                                          const float* __restrict__ e1b,
                                          const int* __restrict__ cellb,
                                          const float4* __restrict__ vmean4,
                                          const v8s* __restrict__ w1frag,
                                          const v8s* __restrict__ w2frag,
                                          const float* __restrict__ v1,
                                          float* __restrict__ out) {
    __shared__ float s_pf[4][RUN][PSTR];
    int wslot = threadIdx.x >> 6;
    int wave = blockIdx.x * 4 + wslot;
    int j = threadIdx.x & 63;
    int base = wave * RUN;

    PtRegs P = load_pt(pos4, e1b, cellb, vmean4, base, j);

    const int m = j & 15, q = j >> 4;

    const int first = rli(P.vx, 0), last = rli(P.vx, RUN - 1);
    const bool firstExt = (rli(P.vx, 17) == first);
    const bool lastExt  = (rli(P.vx, 16) == last);

    // Per-lane segment bounds for point m (ballot over run boundaries).
    int vx_m = __builtin_amdgcn_ds_bpermute(m << 2, P.vx);
    int vx_prev = __shfl_up(P.vx, 1, 64);
    unsigned long long B =
        __ballot((j < RUN) && ((j == 0) || (P.vx != vx_prev)));
    int s_seg = 63 - __builtin_clzll(B & ((2ULL << m) - 1ULL));
    int e_seg = m + 1 + (int)__builtin_ctzll((B | (1ULL << RUN)) >> (m + 1));
    const bool ext_m = (vx_m == first && firstExt) || (vx_m == last && lastExt);

    phase1_mfma(s_pf[wslot], P, w1frag, j);

    // ext lanes: issue global seam-row loads now (covered by local loop below)
    float vf[16];
    if (ext_m) {
        const float* vr = v1 + (size_t)vx_m * 64 + q * 8;
        #pragma unroll
        for (int c = 0; c < 2; c++)
            #pragma unroll
            for (int i = 0; i < 8; i++) vf[c * 8 + i] = vr[c * 32 + i];
    }

    // A-frags: chunks 0,1 = pf1 rows (lane-distinct LDS reads)
    v8s ah[4], al[4];
    #pragma unroll
    for (int c = 0; c < 2; c++) {
        float f[8];
        #pragma unroll
        for (int i = 0; i < 8; i++) f[i] = s_pf[wslot][m][c * 32 + q * 8 + i];
        split8(f, ah[c], al[c]);
    }
    // interior lanes: v1 row = local segment max over own pf1 (identical set)
    if (!ext_m) {
        #pragma unroll
        for (int i = 0; i < 16; i++) vf[i] = 0.f;
        for (int p = s_seg; p < e_seg; p++) {
            const float* row = s_pf[wslot][p];
            float4 a0 = *(const float4*)&row[q * 8];
            float4 a1 = *(const float4*)&row[q * 8 + 4];
            float4 b0 = *(const float4*)&row[32 + q * 8];
            float4 b1 = *(const float4*)&row[32 + q * 8 + 4];
            vf[0] = fmaxf(vf[0], a0.x);  vf[1] = fmaxf(vf[1], a0.y);
            vf[2] = fmaxf(vf[2], a0.z);  vf[3] = fmaxf(vf[3], a0.w);
            vf[4] = fmaxf(vf[4], a1.x);  vf[5] = fmaxf(vf[5], a1.y);
            vf[6] = fmaxf(vf[6], a1.z);  vf[7] = fmaxf(vf[7], a1.w);
            vf[8] = fmaxf(vf[8], b0.x);  vf[9] = fmaxf(vf[9], b0.y);
            vf[10] = fmaxf(vf[10], b0.z); vf[11] = fmaxf(vf[11], b0.w);
            vf[12] = fmaxf(vf[12], b1.x); vf[13] = fmaxf(vf[13], b1.y);
            vf[14] = fmaxf(vf[14], b1.z); vf[15] = fmaxf(vf[15], b1.w);
        }
    }
    // chunks 2,3 = v1 row (segment-constant: rides inside the acc)
    split8(vf + 0, ah[2], al[2]);
    split8(vf + 8, ah[3], al[3]);
    __builtin_amdgcn_wave_barrier();   // A reads done before D overwrites s_pf

    #pragma unroll
    for (int t = 0; t < 4; t++) {
        v8s bh[4], bl[4];
        #pragma unroll
        for (int c = 0; c < 4; c++) {
            bh[c] = w2frag[((t * 4 + c) * 2 + 0) * 64 + j];
            bl[c] = w2frag[((t * 4 + c) * 2 + 1) * 64 + j];
        }
        v4f acc = {0.f, 0.f, 0.f, 0.f};
        #pragma unroll
        for (int c = 0; c < 4; c++) {
            acc = __builtin_amdgcn_mfma_f32_16x16x32_bf16(ah[c], bh[c], acc, 0, 0, 0);
            acc = __builtin_amdgcn_mfma_f32_16x16x32_bf16(al[c], bh[c], acc, 0, 0, 0);
            acc = __builtin_amdgcn_mfma_f32_16x16x32_bf16(ah[c], bl[c], acc, 0, 0, 0);
        }
        #pragma unroll
        for (int r = 0; r < 4; r++) s_pf[wslot][q * 4 + r][t * 16 + m] = acc[r];
    }
    __builtin_amdgcn_wave_barrier();

    int vprev = first;
    float smax = -3.4e38f;
    for (int p = 0; p < RUN; p++) {
        int vp = rli(P.vx, p);
        if (vp != vprev) {
            float r = fmaxf(smax, 0.f);
            size_t o = (size_t)vprev * 64 + j;
            bool ua = (vprev == first && firstExt) || (vprev == last && lastExt);
            if (ua) atomicMax((int*)out + o, __float_as_int(r));
            else out[o] = r;
            vprev = vp; smax = -3.4e38f;
        }
        smax = fmaxf(smax, s_pf[wslot][p][j]);
    }
    {
        float r = fmaxf(smax, 0.f);
        size_t o = (size_t)vprev * 64 + j;
        bool ua = (vprev == first && firstExt) || (vprev == last && lastExt);
        if (ua) atomicMax((int*)out + o, __float_as_int(r));
        else out[o] = r;
    }
}

extern "C" void kernel_launch(void* const* d_in, const int* in_sizes, int n_in,
                              void* d_out, int out_size, void* d_ws, size_t ws_size,
                              hipStream_t stream) {
    const float* pts = (const float*)d_in[0];
    const float* W1  = (const float*)d_in[1];
    const float* W2  = (const float*)d_in[2];
    float* out = (float*)d_out;

    float4* vmean4 = (float4*)d_ws;                         // CANVAS float4
    float*  v1     = (float*)(vmean4 + CANVASc);            // CANVAS*64
    float4* pos4   = (float4*)(v1 + (size_t)CANVASc * 64);  // NPTS float4
    float*  e1b    = (float*)(pos4 + NPTS);                 // NPTS
    int*    cellb  = (int*)(e1b + NPTS);                    // NPTS
    v8s*    w2frag = (v8s*)(cellb + NPTS);                  // 2048 v8s
    v8s*    w1frag = w2frag + 2048;                         // 512 v8s
    int*    cnt    = (int*)(w1frag + 512);                  // CANVAS
    int*    gcur   = cnt + CANVASc;                         // 1
    int*    cursor = gcur + 1;                              // CANVAS

    hipMemsetAsync(cnt, 0, (size_t)(CANVASc + 1) * 4, stream);      // cnt + gcur

    k_stats  <<<GPTS + 5, 256, 0, stream>>>(pts, cnt, W1, W2, w1frag, w2frag);
    k_alloc  <<<GVOX, 256, 0, stream>>>(cnt, cursor, gcur);
    k_scatter<<<GPTS, 256, 0, stream>>>(pts, cursor, pos4, e1b, cellb);
    kV       <<<GVOX + GSEAM, 256, 0, stream>>>(cnt, cursor, pos4, cellb,
                                                vmean4, (float4*)v1, (float4*)out);
    kA       <<<NRUNS / 4, 256, 0, stream>>>(pos4, e1b, cellb, vmean4, w1frag, v1);
    kB       <<<NRUNS / 4, 256, 0, stream>>>(pos4, e1b, cellb, vmean4, w1frag,
                                             w2frag, v1, out);
}